// Round 9
// baseline (349.982 us; speedup 1.0000x reference)
//
#include <hip/hip_runtime.h>

typedef _Float16 half4 __attribute__((ext_vector_type(4)));
typedef _Float16 half8 __attribute__((ext_vector_type(8)));
typedef _Float16 h2pk __attribute__((ext_vector_type(2)));
typedef float f32x4 __attribute__((ext_vector_type(4)));

#define MFMA_F16K32(a, b, c) __builtin_amdgcn_mfma_f32_16x16x32_f16(a, b, c, 0, 0, 0)
#define EXP2F(x) __builtin_amdgcn_exp2f(x)
#define CVT_PK(a, b) __builtin_bit_cast(h2pk, __builtin_amdgcn_cvt_pkrtz(a, b))

constexpr int NSEQ = 2048, DIM = 1024;
constexpr float QSCALE = 11.5415603271f;  // 8 * log2(e): logits in log2 units

__device__ __forceinline__ void ld_lds16(void* lds, const void* g) {
  __builtin_amdgcn_global_load_lds(
      (const __attribute__((address_space(1))) void*)g,
      (__attribute__((address_space(3))) void*)lds, 16, 0, 0);
}

// ---------------------------------------------------------------------------
// prep: blocks 0..1023 transpose weights 64x64 -> fp16 WT[3072][1024] / WoT;
// blocks 1024..3071: x -> fp16.
// ---------------------------------------------------------------------------
__global__ __launch_bounds__(256) void prep(
    const float* __restrict__ w_q, const float* __restrict__ w_vk,
    const float* __restrict__ w_out, const float* __restrict__ x,
    _Float16* __restrict__ WT, _Float16* __restrict__ WoT,
    _Float16* __restrict__ xf) {
  const int bid = blockIdx.x;
  const int t = threadIdx.x;
  if (bid >= 1024) {  // ---- x -> fp16 ----
    const size_t i = ((size_t)(bid - 1024) * 256 + t) * 8;
    float4 a = *(const float4*)(x + i), b2 = *(const float4*)(x + i + 4);
    float v[8] = {a.x, a.y, a.z, a.w, b2.x, b2.y, b2.z, b2.w};
    half8 h;
#pragma unroll
    for (int j = 0; j < 8; ++j) h[j] = (_Float16)v[j];
    *(half8*)(xf + i) = h;
    return;
  }
  __shared__ float T[64][65];
  const int bx = bid & 63, k0 = (bid >> 6) * 64;
  const float* src;
  int srcN, n0, dstrow, mode;
  float scale;
  if (bx < 16) {
    src = w_q; srcN = 1024; n0 = bx * 64; dstrow = n0; scale = QSCALE; mode = 0;
  } else if (bx < 48) {
    src = w_vk; srcN = 2048; n0 = (bx - 16) * 64; dstrow = 1024 + n0;
    scale = 1.0f; mode = 0;
  } else {
    src = w_out; srcN = 1024; n0 = (bx - 48) * 64; dstrow = n0;
    scale = 1.0f; mode = 1;
  }
  {
    const int r = t >> 2, c4 = (t & 3) * 16;
    const float* s = src + (size_t)(k0 + r) * srcN + n0 + c4;
    float4 v0 = ((const float4*)s)[0], v1 = ((const float4*)s)[1],
           v2 = ((const float4*)s)[2], v3 = ((const float4*)s)[3];
    *(float4*)&T[r][c4 + 0] = v0;  *(float4*)&T[r][c4 + 4] = v1;
    *(float4*)&T[r][c4 + 8] = v2;  *(float4*)&T[r][c4 + 12] = v3;
  }
  __syncthreads();
  const int rn = t >> 2, kc = (t & 3) * 16;
  half8 hv[2];
#pragma unroll
  for (int hh = 0; hh < 2; ++hh)
#pragma unroll
    for (int j = 0; j < 8; ++j)
      hv[hh][j] = (_Float16)(T[kc + hh * 8 + j][rn] * scale);
  _Float16* d = ((mode == 0) ? WT + (size_t)(dstrow + rn) * 1024
                             : WoT + (size_t)(n0 + rn) * 1024) + k0 + kc;
  *(half8*)d = hv[0]; *(half8*)(d + 8) = hv[1];
}

// ---------------------------------------------------------------------------
// Fused q/k/v projection. 128x128 tile, BK=32, double-buffered, 4 blocks/CU,
// XCD-swizzled grid. q/k: swapped MFMA operands -> half4 coalesced stores.
// v: original orientation + LDS transpose -> coalesced vT stores.
// ---------------------------------------------------------------------------
__global__ __launch_bounds__(256, 4) void proj6(
    const _Float16* __restrict__ xf, const _Float16* __restrict__ WT,
    _Float16* __restrict__ qb, _Float16* __restrict__ kb,
    _Float16* __restrict__ VT) {
  __shared__ __align__(16) char smem[32768];  // 2 bufs x (X 8KB | B 8KB)
  const int t = threadIdx.x;
  const int lane = t & 63, wave = t >> 6, quad = lane >> 4, lq = lane & 15;
  // XCD swizzle: 768 blocks, 96 consecutive per XCD (4 bm x 24 bn).
  const int wid0 = blockIdx.x + 24 * blockIdx.y;
  const int wid = (wid0 & 7) * 96 + (wid0 >> 3);
  const int bn = (wid % 24) * 128, bm = (wid / 24) * 128;
  const int kind = bn >> 10;
  const int wm = (wave >> 1) * 64, wn = (wave & 1) * 64;

  // staging: 64B rows (32 fp16); one 1KB issue = 16 rows, 4 lanes/row.
  const int srow = lane >> 2;                // 0..15
  const int schk = (lane & 3) ^ (srow & 3);  // 16B chunk
  const _Float16* xg = xf + (size_t)(bm + wave * 32 + srow) * DIM + schk * 8;
  const _Float16* bg = WT + (size_t)(bn + wave * 32 + srow) * DIM + schk * 8;
  const int wb = wave * 2048;  // 32 rows x 64B

  auto issue = [&](char* buf, int k0) {
    ld_lds16(buf + wb,                xg + k0);
    ld_lds16(buf + wb + 1024,         xg + k0 + 16 * DIM);
    ld_lds16(buf + 8192 + wb,         bg + k0);
    ld_lds16(buf + 8192 + wb + 1024,  bg + k0 + 16 * DIM);
  };

  const int swz = (quad ^ (lq & 3)) * 8;  // chunk c of row r at c^(r&3)

  f32x4 acc[4][4];
#pragma unroll
  for (int i = 0; i < 4; ++i)
#pragma unroll
    for (int j = 0; j < 4; ++j) acc[i][j] = (f32x4){0.f, 0.f, 0.f, 0.f};

  char* bufA = smem;
  char* bufB = smem + 16384;
  issue(bufA, 0);
  if (kind == 2) {  // ---- v: original operand order ----
    for (int k0 = 0; k0 < DIM; k0 += 32) {
      char* cur = ((k0 >> 5) & 1) ? bufB : bufA;
      char* nxt = ((k0 >> 5) & 1) ? bufA : bufB;
      __syncthreads();
      if (k0 + 32 < DIM) issue(nxt, k0 + 32);
      const _Float16* Xs = (const _Float16*)cur;
      const _Float16* Bs = (const _Float16*)(cur + 8192);
      half8 ah[4];
#pragma unroll
      for (int i = 0; i < 4; ++i)
        ah[i] = *(const half8*)&Xs[(wm + i * 16 + lq) * 32 + swz];
#pragma unroll
      for (int j = 0; j < 4; ++j) {
        half8 bf = *(const half8*)&Bs[(wn + j * 16 + lq) * 32 + swz];
#pragma unroll
        for (int i = 0; i < 4; ++i)
          acc[i][j] = MFMA_F16K32(ah[i], bf, acc[i][j]);
      }
    }
  } else {  // ---- q/k: swapped operands (token=lq, col=quad*4+r) ----
    for (int k0 = 0; k0 < DIM; k0 += 32) {
      char* cur = ((k0 >> 5) & 1) ? bufB : bufA;
      char* nxt = ((k0 >> 5) & 1) ? bufA : bufB;
      __syncthreads();
      if (k0 + 32 < DIM) issue(nxt, k0 + 32);
      const _Float16* Xs = (const _Float16*)cur;
      const _Float16* Bs = (const _Float16*)(cur + 8192);
      half8 ah[4];
#pragma unroll
      for (int i = 0; i < 4; ++i)
        ah[i] = *(const half8*)&Xs[(wm + i * 16 + lq) * 32 + swz];
#pragma unroll
      for (int j = 0; j < 4; ++j) {
        half8 bf = *(const half8*)&Bs[(wn + j * 16 + lq) * 32 + swz];
#pragma unroll
        for (int i = 0; i < 4; ++i)
          acc[i][j] = MFMA_F16K32(bf, ah[i], acc[i][j]);
      }
    }
  }

  if (kind == 2) {
    // v -> vT[b][h][d][n] via LDS transpose; two 64-token passes.
    _Float16* Ols = (_Float16*)smem;  // 128*68*2 = 17408B <= 32KB
    const int cb = bn - 2048;         // global col base (h*64+d space)
    __syncthreads();                  // all waves done reading K-loop bufs
#pragma unroll
    for (int pass = 0; pass < 2; ++pass) {
      if ((wave >> 1) == pass) {  // waves whose wm == pass*64
#pragma unroll
        for (int i = 0; i < 4; ++i)
#pragma unroll
          for (int j = 0; j < 4; ++j) {
            const int c = wn + j * 16 + lq;    // 0..127
            const int tl = i * 16 + quad * 4;  // token local 0..63
            half4 o;
#pragma unroll
            for (int r = 0; r < 4; ++r) o[r] = (_Float16)acc[i][j][r];
            *(half4*)&Ols[c * 68 + tl] = o;
          }
      }
      __syncthreads();
      {
        const int c = t >> 1, hf = t & 1;  // c 0..127, 32-token half
        const int gcol = cb + c;
        const int tok0 = bm + pass * 64 + hf * 32;
        const int b2 = tok0 >> 11, n2 = tok0 & 2047;
        const _Float16* src = &Ols[c * 68 + hf * 32];
        half8 v0 = ((const half8*)src)[0], v1 = ((const half8*)src)[1],
              v2 = ((const half8*)src)[2], v3 = ((const half8*)src)[3];
        _Float16* dst =
            VT + ((size_t)(b2 * 16 + (gcol >> 6)) * 64 + (gcol & 63)) * 2048 + n2;
        ((half8*)dst)[0] = v0; ((half8*)dst)[1] = v1;
        ((half8*)dst)[2] = v2; ((half8*)dst)[3] = v3;
      }
      __syncthreads();  // before next pass overwrites Ols
    }
  } else {
    // q/k coalesced: half4 over r = 4 consecutive cols; 16 rows x 32B/inst.
    _Float16* D = (kind == 0) ? qb : kb;
    const int cb = bn & 1023;
#pragma unroll
    for (int i = 0; i < 4; ++i) {
      const int row = bm + wm + i * 16 + lq;
#pragma unroll
      for (int j = 0; j < 4; ++j) {
        const int col = cb + wn + j * 16 + quad * 4;
        half4 o;
#pragma unroll
        for (int r = 0; r < 4; ++r) o[r] = (_Float16)acc[i][j][r];
        *(half4*)&D[(size_t)row * 1024 + col] = o;
      }
    }
  }
}

// ---------------------------------------------------------------------------
// Flash attention attn10 = attn9 + T15 software pipeline: S for tile p+1 is
// computed one iteration AHEAD; softmax(s_p) at the top of iter p reads
// scores produced a full iteration ago (MFMA latency fully hidden), then
// QK^T(p+1) overwrites s, then PV(p). K stays double-buffered (K[x] read
// one iter after landing, freed across a barrier); V is TRI-buffered
// (V[p+2]'s DMA now overlaps PV(p)'s reads of vb[p%3]).
// LDS: 2 groups x (2x8K K + 3x8K V) = 80KB -> exactly 2 blocks/CU.
// ---------------------------------------------------------------------------
__global__ __launch_bounds__(512, 4) void attn10(
    const _Float16* __restrict__ qb, const _Float16* __restrict__ kb,
    const _Float16* __restrict__ vT, _Float16* __restrict__ ho) {
  __shared__ __align__(16) char smem[81920];
  const int t = threadIdx.x;
  const int lane = t & 63, wave = t >> 6, quad = lane >> 4, lq = lane & 15;
  const int group = wave >> 2, wq = wave & 3;
  const int wid = blockIdx.x + 16 * blockIdx.y;  // 0..511
  const int xcd = wid & 7, slot = wid >> 3;      // slot 0..63
  const int i0 = (slot & 15) * 128;
  const int bh = xcd + 8 * (slot >> 4);
  const int b = bh >> 4, head = bh & 15;
  const size_t rowbase = (size_t)b * NSEQ;

  half8 qf[2][2];
#pragma unroll
  for (int qt = 0; qt < 2; ++qt) {
    const _Float16* qp =
        qb + (rowbase + i0 + wq * 32 + qt * 16 + lq) * DIM + head * 64 + quad * 8;
    qf[qt][0] = *(const half8*)qp;
    qf[qt][1] = *(const half8*)(qp + 32);
  }

  f32x4 o[2][4];
#pragma unroll
  for (int qt = 0; qt < 2; ++qt)
#pragma unroll
    for (int dt = 0; dt < 4; ++dt) o[qt][dt] = (f32x4){0.f, 0.f, 0.f, 0.f};
  float mrun[2] = {-3.0e38f, -3.0e38f};
  float lrun[2] = {0.f, 0.f};

  // staging addresses (same as attn9; kappa row permutation for K32 PV)
  const int srow = lane >> 3, schk = (lane & 7) ^ srow;
  const int krow = (wq >> 1) * 32 + (wq & 1) * 4 + ((srow & 4) << 1) + (srow & 3);
  const _Float16* kgp =
      kb + (rowbase + krow) * DIM + head * 64 + schk * 8;
  const int vrow = lane >> 3;
  const int vchk = (lane & 7) ^ vrow;
  const _Float16* vgp =
      vT + ((size_t)bh * 64 + wq * 16 + vrow) * 2048 + vchk * 8;

  // buffers: per group 2x8K K + 3x8K V = 40KB
  char* gb = smem + group * 40960;
  char* kbf0 = gb;          char* kbf1 = gb + 8192;
  char* vbf0 = gb + 16384;  char* vbf1 = gb + 24576;  char* vbf2 = gb + 32768;

  auto issueK = [&](char* buf, int tile) {
    const int j = (2 * tile + group) * 64;
    char* kd = buf + wq * 2048;
    ld_lds16(kd,        kgp + (size_t)j * DIM);
    ld_lds16(kd + 1024, kgp + (size_t)(j + 16) * DIM);
  };
  auto issueV = [&](char* buf, int tile) {
    const int j = (2 * tile + group) * 64;
    char* vd = buf + wq * 2048;
    ld_lds16(vd,        vgp + j);
    ld_lds16(vd + 1024, vgp + 8 * 2048 + j);
  };

  const int swzK0 = (quad ^ (lq & 7)) * 8;
  const int swzK1 = ((quad + 4) ^ (lq & 7)) * 8;

  f32x4 s[2][4];
  auto QKT = [&](const char* kbuf) {
    const _Float16* Khs = (const _Float16*)kbuf;
    __builtin_amdgcn_s_setprio(1);
#pragma unroll
    for (int nt = 0; nt < 4; ++nt) {
      const int roff = (nt * 16 + lq) * 64;
      half8 k0f = *(const half8*)&Khs[roff + swzK0];
      half8 k1f = *(const half8*)&Khs[roff + swzK1];
#pragma unroll
      for (int qt = 0; qt < 2; ++qt) {
        f32x4 sv = (f32x4){0.f, 0.f, 0.f, 0.f};
        sv = MFMA_F16K32(k0f, qf[qt][0], sv);
        sv = MFMA_F16K32(k1f, qf[qt][1], sv);
        s[qt][nt] = sv;
      }
    }
    __builtin_amdgcn_s_setprio(0);
  };

  // prologue: stage tiles 0 and 1; compute s for tile 0
  issueK(kbf0, 0); issueV(vbf0, 0);
  __syncthreads();
  issueK(kbf1, 1); issueV(vbf1, 1);
  QKT(kbf0);

  char* kbufs[2] = {kbf0, kbf1};
  char* vbufs[3] = {vbf0, vbf1, vbf2};

  for (int p = 0; p < 16; ++p) {
    __syncthreads();  // K[p+1], V[p+1] landed; all group waves done with
                      // kbufs[p&1] (read at p-1) and vbufs[(p+2)%3] (p-1)
    if (p <= 13) {
      issueK(kbufs[p & 1], p + 2);
      issueV(vbufs[(p + 2) % 3], p + 2);
    }

    // softmax of tile p (scores computed one iteration ago -> no MFMA stall)
    half8 pa8[2][2];
#pragma unroll
    for (int qt = 0; qt < 2; ++qt) {
      float m0 = fmaxf(fmaxf(s[qt][0][0], s[qt][0][1]),
                       fmaxf(s[qt][0][2], s[qt][0][3]));
      float m1 = fmaxf(fmaxf(s[qt][1][0], s[qt][1][1]),
                       fmaxf(s[qt][1][2], s[qt][1][3]));
      float m2 = fmaxf(fmaxf(s[qt][2][0], s[qt][2][1]),
                       fmaxf(s[qt][2][2], s[qt][2][3]));
      float m3 = fmaxf(fmaxf(s[qt][3][0], s[qt][3][1]),
                       fmaxf(s[qt][3][2], s[qt][3][3]));
      float mx = fmaxf(fmaxf(m0, m1), fmaxf(m2, m3));
      mx = fmaxf(mx, __shfl_xor(mx, 16));
      mx = fmaxf(mx, __shfl_xor(mx, 32));
      const float mn = fmaxf(mrun[qt], mx);
      const float alpha = EXP2F(mrun[qt] - mn);
      mrun[qt] = mn;
      float rs = 0.f;
#pragma unroll
      for (int nt = 0; nt < 4; ++nt) {
        float p0 = EXP2F(s[qt][nt][0] - mn), p1 = EXP2F(s[qt][nt][1] - mn);
        float p2 = EXP2F(s[qt][nt][2] - mn), p3 = EXP2F(s[qt][nt][3] - mn);
        rs += (p0 + p1) + (p2 + p3);
        h2pk lo = CVT_PK(p0, p1);
        h2pk hi = CVT_PK(p2, p3);
        const int bb = nt >> 1, e = (nt & 1) * 4;
        pa8[qt][bb][e + 0] = lo[0]; pa8[qt][bb][e + 1] = lo[1];
        pa8[qt][bb][e + 2] = hi[0]; pa8[qt][bb][e + 3] = hi[1];
      }
      rs += __shfl_xor(rs, 16);
      rs += __shfl_xor(rs, 32);
      lrun[qt] = lrun[qt] * alpha + rs;
#pragma unroll
      for (int dt = 0; dt < 4; ++dt) o[qt][dt] *= alpha;
    }

    // S for tile p+1 (overwrites s; consumed next iteration)
    if (p <= 14) QKT(kbufs[(p + 1) & 1]);

    // PV of tile p
    {
      const _Float16* Vts = (const _Float16*)vbufs[p % 3];
      __builtin_amdgcn_s_setprio(1);
#pragma unroll
      for (int dt = 0; dt < 4; ++dt) {
        const int vr2 = (dt * 16 + lq) * 64;
#pragma unroll
        for (int bb = 0; bb < 2; ++bb) {
          const int voff = vr2 + (((bb * 4 + quad) ^ (lq & 7)) * 8);
          half8 va = *(const half8*)&Vts[voff];
          o[0][dt] = MFMA_F16K32(va, pa8[0][bb], o[0][dt]);
          o[1][dt] = MFMA_F16K32(va, pa8[1][bb], o[1][dt]);
        }
      }
      __builtin_amdgcn_s_setprio(0);
    }
  }

  // ---- merge the two key-parity partials (waves wq and wq+4 share q-rows)
  float* dump = (float*)smem;  // 4 waves x 64 lanes x 36 f32 = 36864B
  __syncthreads();             // all waves done with final tile reads
  if (group == 1) {
    float* D = dump + wq * 2304 + lane * 36;
#pragma unroll
    for (int qt = 0; qt < 2; ++qt)
#pragma unroll
      for (int dt = 0; dt < 4; ++dt)
        *(f32x4*)(D + (qt * 4 + dt) * 4) = o[qt][dt];
    D[32] = mrun[0]; D[33] = lrun[0]; D[34] = mrun[1]; D[35] = lrun[1];
  }
  __syncthreads();
  _Float16* Ots = (_Float16*)(smem + 40960);  // [128][80] f16 = 20480B
  if (group == 0) {
    const float* D = dump + wq * 2304 + lane * 36;
#pragma unroll
    for (int qt = 0; qt < 2; ++qt) {
      const float m2 = D[32 + qt * 2], l2 = D[33 + qt * 2];
      const float mM = fmaxf(mrun[qt], m2);
      const float f1 = EXP2F(mrun[qt] - mM);
      const float f2 = EXP2F(m2 - mM);
      const float inv = 1.0f / (lrun[qt] * f1 + l2 * f2);
#pragma unroll
      for (int dt = 0; dt < 4; ++dt) {
        f32x4 o2 = *(const f32x4*)(D + (qt * 4 + dt) * 4);
#pragma unroll
        for (int r = 0; r < 4; ++r) {
          const float val = (o[qt][dt][r] * f1 + o2[r] * f2) * inv;
          Ots[(wq * 32 + qt * 16 + lq) * 80 + dt * 16 + quad * 4 + r] =
              (_Float16)val;
        }
      }
    }
  }
  __syncthreads();
  {
    const int row = t >> 2, seg = t & 3;
    const _Float16* src = &Ots[row * 80 + seg * 16];
    half8 o0 = ((const half8*)src)[0], o1 = ((const half8*)src)[1];
    _Float16* dst = ho + (rowbase + i0 + row) * DIM + head * 64 + seg * 16;
    ((half8*)dst)[0] = o0; ((half8*)dst)[1] = o1;
  }
}

// ---------------------------------------------------------------------------
// out = ho(fp16) @ w_out — 64x128 tile, swapped MFMA operands -> float4
// coalesced C stores; XCD-swizzled grid.
// ---------------------------------------------------------------------------
__global__ __launch_bounds__(256, 4) void gemm_out(
    const _Float16* __restrict__ A, const _Float16* __restrict__ BT,
    float* __restrict__ C) {
  __shared__ __align__(16) char smem[24576];  // 2 bufs: A 4KB | B 8KB
  const int t = threadIdx.x;
  const int lane = t & 63, wave = t >> 6, quad = lane >> 4, lq = lane & 15;
  // XCD swizzle: 512 blocks, 64 consecutive per XCD (8 bm x 8 bn).
  const int wid0 = blockIdx.x + 8 * blockIdx.y;
  const int wid = (wid0 & 7) * 64 + (wid0 >> 3);
  const int bn = (wid % 8) * 128, bm = (wid / 8) * 64;
  const int wm = (wave >> 1) * 32, wn = (wave & 1) * 64;

  const int bco = (lane & 7) ^ (lane >> 3);
  const int brow = 2 * (lane >> 3) + (bco >> 2);
  const int bcc = bco & 3;
  const _Float16* ag = A + (size_t)(bm + wave * 16 + brow) * DIM + bcc * 8;
  const _Float16* bg = BT + (size_t)(bn + wave * 32 + brow) * DIM + bcc * 8;
  const int swzB = ((((lq & 1) << 2) | quad) ^ ((lq >> 1) & 7)) * 8;

  auto issue = [&](char* buf, int k0) {
    ld_lds16(buf + wave * 1024,               ag + k0);
    ld_lds16(buf + 4096 + wave * 2048,        bg + k0);
    ld_lds16(buf + 4096 + wave * 2048 + 1024, bg + k0 + 16 * DIM);
  };

  f32x4 acc[2][4];
#pragma unroll
  for (int i = 0; i < 2; ++i)
#pragma unroll
    for (int j = 0; j < 4; ++j) acc[i][j] = (f32x4){0.f, 0.f, 0.f, 0.f};

  char* bufA = smem;
  char* bufB = smem + 12288;
  issue(bufA, 0);
  for (int k0 = 0; k0 < DIM; k0 += 32) {
    char* cur = ((k0 >> 5) & 1) ? bufB : bufA;
    char* nxt = ((k0 >> 5) & 1) ? bufA : bufB;
    __syncthreads();
    if (k0 + 32 < DIM) issue(nxt, k0 + 32);
    const _Float16* Ahs = (const _Float16*)cur;
    const _Float16* Bhs = (const _Float16*)(cur + 4096);
    half8 ah[2];
#pragma unroll
    for (int i = 0; i < 2; ++i) {
      const int row = wm + i * 16 + lq;
      ah[i] = *(const half8*)&Ahs[(row >> 1) * 64 + swzB];
    }
#pragma unroll
    for (int j = 0; j < 4; ++j) {
      const int row = wn + j * 16 + lq;
      half8 bf = *(const half8*)&Bhs[(row >> 1) * 64 + swzB];
#pragma unroll
      for (int i = 0; i < 2; ++i)
        acc[i][j] = MFMA_F16K32(bf, ah[i], acc[i][j]);  // swapped: row=lq
    }
  }
#pragma unroll
  for (int i = 0; i < 2; ++i) {
    const int row = bm + wm + i * 16 + lq;
#pragma unroll
    for (int j = 0; j < 4; ++j) {
      const int col = bn + wn + j * 16 + quad * 4;
      *(f32x4*)&C[(size_t)row * 1024 + col] = acc[i][j];
    }
  }
}

// ---------------------------------------------------------------------------
extern "C" void kernel_launch(void* const* d_in, const int* in_sizes, int n_in,
                              void* d_out, int out_size, void* d_ws,
                              size_t ws_size, hipStream_t stream) {
  const float* x     = (const float*)d_in[0];
  const float* w_q   = (const float*)d_in[1];
  const float* w_vk  = (const float*)d_in[2];
  const float* w_out = (const float*)d_in[3];
  float* out = (float*)d_out;

  char* w = (char*)d_ws;  // 48 MB used
  _Float16* wT  = (_Float16*)(w);                  // [3072][1024] 6MB
  _Float16* woT = (_Float16*)(w + (6ull << 20));   // [1024][1024] 2MB
  _Float16* qbb = (_Float16*)(w + (8ull << 20));   // [4096][1024] 8MB
  _Float16* kbb = (_Float16*)(w + (16ull << 20));  // [4096][1024] 8MB
  _Float16* vTb = (_Float16*)(w + (24ull << 20));  // [b][h][64][2048] 8MB
  _Float16* hob = (_Float16*)(w + (32ull << 20));  // [4096][1024] 8MB
  _Float16* xfb = (_Float16*)(w + (40ull << 20));  // [4096][1024] 8MB

  dim3 blk(256);
  prep<<<dim3(3072), blk, 0, stream>>>(w_q, w_vk, w_out, x, wT, woT, xfb);
  proj6<<<dim3(24, 32), blk, 0, stream>>>(xfb, wT, qbb, kbb, vTb);
  attn10<<<dim3(16, 32), dim3(512), 0, stream>>>(qbb, kbb, vTb, hob);
  gemm_out<<<dim3(8, 64), blk, 0, stream>>>(hob, woT, out);
}

// Round 10
// 238.495 us; speedup vs baseline: 1.4675x; 1.4675x over previous
//
#include <hip/hip_runtime.h>

typedef _Float16 half4 __attribute__((ext_vector_type(4)));
typedef _Float16 half8 __attribute__((ext_vector_type(8)));
typedef _Float16 h2pk __attribute__((ext_vector_type(2)));
typedef float f32x4 __attribute__((ext_vector_type(4)));

#define MFMA_F16K32(a, b, c) __builtin_amdgcn_mfma_f32_16x16x32_f16(a, b, c, 0, 0, 0)
#define EXP2F(x) __builtin_amdgcn_exp2f(x)
#define CVT_PK(a, b) __builtin_bit_cast(h2pk, __builtin_amdgcn_cvt_pkrtz(a, b))

constexpr int NSEQ = 2048, DIM = 1024;
constexpr float QSCALE = 11.5415603271f;  // 8 * log2(e): logits in log2 units

__device__ __forceinline__ void ld_lds16(void* lds, const void* g) {
  __builtin_amdgcn_global_load_lds(
      (const __attribute__((address_space(1))) void*)g,
      (__attribute__((address_space(3))) void*)lds, 16, 0, 0);
}

// ---------------------------------------------------------------------------
// prep: blocks 0..1023 transpose weights 64x64 -> fp16 WT[3072][1024] / WoT;
// blocks 1024..3071: x -> fp16.
// ---------------------------------------------------------------------------
__global__ __launch_bounds__(256) void prep(
    const float* __restrict__ w_q, const float* __restrict__ w_vk,
    const float* __restrict__ w_out, const float* __restrict__ x,
    _Float16* __restrict__ WT, _Float16* __restrict__ WoT,
    _Float16* __restrict__ xf) {
  const int bid = blockIdx.x;
  const int t = threadIdx.x;
  if (bid >= 1024) {  // ---- x -> fp16 ----
    const size_t i = ((size_t)(bid - 1024) * 256 + t) * 8;
    float4 a = *(const float4*)(x + i), b2 = *(const float4*)(x + i + 4);
    float v[8] = {a.x, a.y, a.z, a.w, b2.x, b2.y, b2.z, b2.w};
    half8 h;
#pragma unroll
    for (int j = 0; j < 8; ++j) h[j] = (_Float16)v[j];
    *(half8*)(xf + i) = h;
    return;
  }
  __shared__ float T[64][65];
  const int bx = bid & 63, k0 = (bid >> 6) * 64;
  const float* src;
  int srcN, n0, dstrow, mode;
  float scale;
  if (bx < 16) {
    src = w_q; srcN = 1024; n0 = bx * 64; dstrow = n0; scale = QSCALE; mode = 0;
  } else if (bx < 48) {
    src = w_vk; srcN = 2048; n0 = (bx - 16) * 64; dstrow = 1024 + n0;
    scale = 1.0f; mode = 0;
  } else {
    src = w_out; srcN = 1024; n0 = (bx - 48) * 64; dstrow = n0;
    scale = 1.0f; mode = 1;
  }
  {
    const int r = t >> 2, c4 = (t & 3) * 16;
    const float* s = src + (size_t)(k0 + r) * srcN + n0 + c4;
    float4 v0 = ((const float4*)s)[0], v1 = ((const float4*)s)[1],
           v2 = ((const float4*)s)[2], v3 = ((const float4*)s)[3];
    *(float4*)&T[r][c4 + 0] = v0;  *(float4*)&T[r][c4 + 4] = v1;
    *(float4*)&T[r][c4 + 8] = v2;  *(float4*)&T[r][c4 + 12] = v3;
  }
  __syncthreads();
  const int rn = t >> 2, kc = (t & 3) * 16;
  half8 hv[2];
#pragma unroll
  for (int hh = 0; hh < 2; ++hh)
#pragma unroll
    for (int j = 0; j < 8; ++j)
      hv[hh][j] = (_Float16)(T[kc + hh * 8 + j][rn] * scale);
  _Float16* d = ((mode == 0) ? WT + (size_t)(dstrow + rn) * 1024
                             : WoT + (size_t)(n0 + rn) * 1024) + k0 + kc;
  *(half8*)d = hv[0]; *(half8*)(d + 8) = hv[1];
}

// ---------------------------------------------------------------------------
// Fused q/k/v projection. 128x128 tile, BK=32, double-buffered, 4 blocks/CU,
// XCD-swizzled grid. q/k: swapped MFMA operands -> half4 coalesced stores.
// v: original orientation + LDS transpose -> coalesced vT stores.
// ---------------------------------------------------------------------------
__global__ __launch_bounds__(256, 4) void proj6(
    const _Float16* __restrict__ xf, const _Float16* __restrict__ WT,
    _Float16* __restrict__ qb, _Float16* __restrict__ kb,
    _Float16* __restrict__ VT) {
  __shared__ __align__(16) char smem[32768];  // 2 bufs x (X 8KB | B 8KB)
  const int t = threadIdx.x;
  const int lane = t & 63, wave = t >> 6, quad = lane >> 4, lq = lane & 15;
  // XCD swizzle: 768 blocks, 96 consecutive per XCD (4 bm x 24 bn).
  const int wid0 = blockIdx.x + 24 * blockIdx.y;
  const int wid = (wid0 & 7) * 96 + (wid0 >> 3);
  const int bn = (wid % 24) * 128, bm = (wid / 24) * 128;
  const int kind = bn >> 10;
  const int wm = (wave >> 1) * 64, wn = (wave & 1) * 64;

  // staging: 64B rows (32 fp16); one 1KB issue = 16 rows, 4 lanes/row.
  const int srow = lane >> 2;                // 0..15
  const int schk = (lane & 3) ^ (srow & 3);  // 16B chunk
  const _Float16* xg = xf + (size_t)(bm + wave * 32 + srow) * DIM + schk * 8;
  const _Float16* bg = WT + (size_t)(bn + wave * 32 + srow) * DIM + schk * 8;
  const int wb = wave * 2048;  // 32 rows x 64B

  auto issue = [&](char* buf, int k0) {
    ld_lds16(buf + wb,                xg + k0);
    ld_lds16(buf + wb + 1024,         xg + k0 + 16 * DIM);
    ld_lds16(buf + 8192 + wb,         bg + k0);
    ld_lds16(buf + 8192 + wb + 1024,  bg + k0 + 16 * DIM);
  };

  const int swz = (quad ^ (lq & 3)) * 8;  // chunk c of row r at c^(r&3)

  f32x4 acc[4][4];
#pragma unroll
  for (int i = 0; i < 4; ++i)
#pragma unroll
    for (int j = 0; j < 4; ++j) acc[i][j] = (f32x4){0.f, 0.f, 0.f, 0.f};

  char* bufA = smem;
  char* bufB = smem + 16384;
  issue(bufA, 0);
  if (kind == 2) {  // ---- v: original operand order ----
    for (int k0 = 0; k0 < DIM; k0 += 32) {
      char* cur = ((k0 >> 5) & 1) ? bufB : bufA;
      char* nxt = ((k0 >> 5) & 1) ? bufA : bufB;
      __syncthreads();
      if (k0 + 32 < DIM) issue(nxt, k0 + 32);
      const _Float16* Xs = (const _Float16*)cur;
      const _Float16* Bs = (const _Float16*)(cur + 8192);
      half8 ah[4];
#pragma unroll
      for (int i = 0; i < 4; ++i)
        ah[i] = *(const half8*)&Xs[(wm + i * 16 + lq) * 32 + swz];
#pragma unroll
      for (int j = 0; j < 4; ++j) {
        half8 bf = *(const half8*)&Bs[(wn + j * 16 + lq) * 32 + swz];
#pragma unroll
        for (int i = 0; i < 4; ++i)
          acc[i][j] = MFMA_F16K32(ah[i], bf, acc[i][j]);
      }
    }
  } else {  // ---- q/k: swapped operands (token=lq, col=quad*4+r) ----
    for (int k0 = 0; k0 < DIM; k0 += 32) {
      char* cur = ((k0 >> 5) & 1) ? bufB : bufA;
      char* nxt = ((k0 >> 5) & 1) ? bufA : bufB;
      __syncthreads();
      if (k0 + 32 < DIM) issue(nxt, k0 + 32);
      const _Float16* Xs = (const _Float16*)cur;
      const _Float16* Bs = (const _Float16*)(cur + 8192);
      half8 ah[4];
#pragma unroll
      for (int i = 0; i < 4; ++i)
        ah[i] = *(const half8*)&Xs[(wm + i * 16 + lq) * 32 + swz];
#pragma unroll
      for (int j = 0; j < 4; ++j) {
        half8 bf = *(const half8*)&Bs[(wn + j * 16 + lq) * 32 + swz];
#pragma unroll
        for (int i = 0; i < 4; ++i)
          acc[i][j] = MFMA_F16K32(bf, ah[i], acc[i][j]);
      }
    }
  }

  if (kind == 2) {
    // v -> vT[b][h][d][n] via LDS transpose; two 64-token passes.
    _Float16* Ols = (_Float16*)smem;  // 128*68*2 = 17408B <= 32KB
    const int cb = bn - 2048;         // global col base (h*64+d space)
    __syncthreads();                  // all waves done reading K-loop bufs
#pragma unroll
    for (int pass = 0; pass < 2; ++pass) {
      if ((wave >> 1) == pass) {  // waves whose wm == pass*64
#pragma unroll
        for (int i = 0; i < 4; ++i)
#pragma unroll
          for (int j = 0; j < 4; ++j) {
            const int c = wn + j * 16 + lq;    // 0..127
            const int tl = i * 16 + quad * 4;  // token local 0..63
            half4 o;
#pragma unroll
            for (int r = 0; r < 4; ++r) o[r] = (_Float16)acc[i][j][r];
            *(half4*)&Ols[c * 68 + tl] = o;
          }
      }
      __syncthreads();
      {
        const int c = t >> 1, hf = t & 1;  // c 0..127, 32-token half
        const int gcol = cb + c;
        const int tok0 = bm + pass * 64 + hf * 32;
        const int b2 = tok0 >> 11, n2 = tok0 & 2047;
        const _Float16* src = &Ols[c * 68 + hf * 32];
        half8 v0 = ((const half8*)src)[0], v1 = ((const half8*)src)[1],
              v2 = ((const half8*)src)[2], v3 = ((const half8*)src)[3];
        _Float16* dst =
            VT + ((size_t)(b2 * 16 + (gcol >> 6)) * 64 + (gcol & 63)) * 2048 + n2;
        ((half8*)dst)[0] = v0; ((half8*)dst)[1] = v1;
        ((half8*)dst)[2] = v2; ((half8*)dst)[3] = v3;
      }
      __syncthreads();  // before next pass overwrites Ols
    }
  } else {
    // q/k coalesced: half4 over r = 4 consecutive cols; 16 rows x 32B/inst.
    _Float16* D = (kind == 0) ? qb : kb;
    const int cb = bn & 1023;
#pragma unroll
    for (int i = 0; i < 4; ++i) {
      const int row = bm + wm + i * 16 + lq;
#pragma unroll
      for (int j = 0; j < 4; ++j) {
        const int col = cb + wn + j * 16 + quad * 4;
        half4 o;
#pragma unroll
        for (int r = 0; r < 4; ++r) o[r] = (_Float16)acc[i][j][r];
        *(half4*)&D[(size_t)row * 1024 + col] = o;
      }
    }
  }
}

// ---------------------------------------------------------------------------
// Flash attention attn11 = attn9 + T15 pipeline, STATIC buffers (round-9's
// runtime-indexed pointer arrays caused scratch spill: FETCH 592MB).
// Per iter p: barrier -> issue K(p+2) into the K-buf freed by last QK^T,
// issue V(p+1) into the V-buf freed by last PV -> softmax(s_p) [scores one
// iteration old: MFMA latency hidden] -> QK^T(p+1) -> PV(p).
// K is consumed one iter after landing (2 bufs); V same (2 bufs). All
// buffer choice by position in a manually 2-unrolled loop: zero dynamic
// indexing. LDS 64KB -> 2 blocks/CU.
// ---------------------------------------------------------------------------
__global__ __launch_bounds__(512, 4) void attn11(
    const _Float16* __restrict__ qb, const _Float16* __restrict__ kb,
    const _Float16* __restrict__ vT, _Float16* __restrict__ ho) {
  __shared__ __align__(16) char smem[65536];
  const int t = threadIdx.x;
  const int lane = t & 63, wave = t >> 6, quad = lane >> 4, lq = lane & 15;
  const int group = wave >> 2, wq = wave & 3;
  const int wid = blockIdx.x + 16 * blockIdx.y;  // 0..511
  const int xcd = wid & 7, slot = wid >> 3;      // slot 0..63
  const int i0 = (slot & 15) * 128;
  const int bh = xcd + 8 * (slot >> 4);
  const int b = bh >> 4, head = bh & 15;
  const size_t rowbase = (size_t)b * NSEQ;

  half8 qf[2][2];
#pragma unroll
  for (int qt = 0; qt < 2; ++qt) {
    const _Float16* qp =
        qb + (rowbase + i0 + wq * 32 + qt * 16 + lq) * DIM + head * 64 + quad * 8;
    qf[qt][0] = *(const half8*)qp;
    qf[qt][1] = *(const half8*)(qp + 32);
  }

  f32x4 o[2][4];
#pragma unroll
  for (int qt = 0; qt < 2; ++qt)
#pragma unroll
    for (int dt = 0; dt < 4; ++dt) o[qt][dt] = (f32x4){0.f, 0.f, 0.f, 0.f};
  float mrun[2] = {-3.0e38f, -3.0e38f};
  float lrun[2] = {0.f, 0.f};

  // staging addresses (kappa row permutation for K32 PV, as attn9)
  const int srow = lane >> 3, schk = (lane & 7) ^ srow;
  const int krow = (wq >> 1) * 32 + (wq & 1) * 4 + ((srow & 4) << 1) + (srow & 3);
  const _Float16* kgp =
      kb + (rowbase + krow) * DIM + head * 64 + schk * 8;
  const int vrow = lane >> 3;
  const int vchk = (lane & 7) ^ vrow;
  const _Float16* vgp =
      vT + ((size_t)bh * 64 + wq * 16 + vrow) * 2048 + vchk * 8;

  // static buffers per group: K x2, V x2 (8KB each) = 32KB
  char* gbase = smem + group * 32768;
  char* ka  = gbase;
  char* kb2 = gbase + 8192;
  char* va  = gbase + 16384;
  char* vb  = gbase + 24576;

  auto issueK = [&](char* buf, int tile) {
    const int j = (2 * tile + group) * 64;
    char* kd = buf + wq * 2048;
    ld_lds16(kd,        kgp + (size_t)j * DIM);
    ld_lds16(kd + 1024, kgp + (size_t)(j + 16) * DIM);
  };
  auto issueV = [&](char* buf, int tile) {
    const int j = (2 * tile + group) * 64;
    char* vd = buf + wq * 2048;
    ld_lds16(vd,        vgp + j);
    ld_lds16(vd + 1024, vgp + 8 * 2048 + j);
  };

  const int swzK0 = (quad ^ (lq & 7)) * 8;
  const int swzK1 = ((quad + 4) ^ (lq & 7)) * 8;

  f32x4 s[2][4];
  auto QKT = [&](const char* kbuf) {
    const _Float16* Khs = (const _Float16*)kbuf;
    __builtin_amdgcn_s_setprio(1);
#pragma unroll
    for (int nt = 0; nt < 4; ++nt) {
      const int roff = (nt * 16 + lq) * 64;
      half8 k0f = *(const half8*)&Khs[roff + swzK0];
      half8 k1f = *(const half8*)&Khs[roff + swzK1];
#pragma unroll
      for (int qt = 0; qt < 2; ++qt) {
        f32x4 sv = (f32x4){0.f, 0.f, 0.f, 0.f};
        sv = MFMA_F16K32(k0f, qf[qt][0], sv);
        sv = MFMA_F16K32(k1f, qf[qt][1], sv);
        s[qt][nt] = sv;
      }
    }
    __builtin_amdgcn_s_setprio(0);
  };

  // one pipeline iteration; buffer roles passed positionally (all static)
  auto iterBody = [&](int p, char* kCur /*K(p+1)*/, char* kFree /*<-K(p+2)*/,
                      char* vCur /*V(p)*/, char* vNext /*<-V(p+1)*/) {
    __syncthreads();  // K(p+1), V(p) landed; kFree/vNext free
    if (p <= 13) issueK(kFree, p + 2);
    if (p <= 14) issueV(vNext, p + 1);

    // softmax of tile p (s computed one iteration ago)
    half8 pa8[2][2];
#pragma unroll
    for (int qt = 0; qt < 2; ++qt) {
      float m0 = fmaxf(fmaxf(s[qt][0][0], s[qt][0][1]),
                       fmaxf(s[qt][0][2], s[qt][0][3]));
      float m1 = fmaxf(fmaxf(s[qt][1][0], s[qt][1][1]),
                       fmaxf(s[qt][1][2], s[qt][1][3]));
      float m2 = fmaxf(fmaxf(s[qt][2][0], s[qt][2][1]),
                       fmaxf(s[qt][2][2], s[qt][2][3]));
      float m3 = fmaxf(fmaxf(s[qt][3][0], s[qt][3][1]),
                       fmaxf(s[qt][3][2], s[qt][3][3]));
      float mx = fmaxf(fmaxf(m0, m1), fmaxf(m2, m3));
      mx = fmaxf(mx, __shfl_xor(mx, 16));
      mx = fmaxf(mx, __shfl_xor(mx, 32));
      const float mn = fmaxf(mrun[qt], mx);
      const float alpha = EXP2F(mrun[qt] - mn);
      mrun[qt] = mn;
      float rs = 0.f;
#pragma unroll
      for (int nt = 0; nt < 4; ++nt) {
        float p0 = EXP2F(s[qt][nt][0] - mn), p1 = EXP2F(s[qt][nt][1] - mn);
        float p2 = EXP2F(s[qt][nt][2] - mn), p3 = EXP2F(s[qt][nt][3] - mn);
        rs += (p0 + p1) + (p2 + p3);
        h2pk lo = CVT_PK(p0, p1);
        h2pk hi = CVT_PK(p2, p3);
        const int bb = nt >> 1, e = (nt & 1) * 4;
        pa8[qt][bb][e + 0] = lo[0]; pa8[qt][bb][e + 1] = lo[1];
        pa8[qt][bb][e + 2] = hi[0]; pa8[qt][bb][e + 3] = hi[1];
      }
      rs += __shfl_xor(rs, 16);
      rs += __shfl_xor(rs, 32);
      lrun[qt] = lrun[qt] * alpha + rs;
#pragma unroll
      for (int dt = 0; dt < 4; ++dt) o[qt][dt] *= alpha;
    }

    // S for tile p+1 (overwrites s; consumed next iteration)
    if (p <= 14) QKT(kCur);

    // PV of tile p
    {
      const _Float16* Vts = (const _Float16*)vCur;
      __builtin_amdgcn_s_setprio(1);
#pragma unroll
      for (int dt = 0; dt < 4; ++dt) {
        const int vr2 = (dt * 16 + lq) * 64;
#pragma unroll
        for (int bb = 0; bb < 2; ++bb) {
          const int voff = vr2 + (((bb * 4 + quad) ^ (lq & 7)) * 8);
          half8 vv = *(const half8*)&Vts[voff];
          o[0][dt] = MFMA_F16K32(vv, pa8[0][bb], o[0][dt]);
          o[1][dt] = MFMA_F16K32(vv, pa8[1][bb], o[1][dt]);
        }
      }
      __builtin_amdgcn_s_setprio(0);
    }
  };

  // prologue: K0 -> ka, V0 -> va; K1 -> kb2; s = QK^T(tile 0)
  issueK(ka, 0); issueV(va, 0);
  __syncthreads();
  issueK(kb2, 1);
  QKT(ka);

  for (int p = 0; p < 16; p += 2) {
    // even iter p:   QK^T reads K(p+1) [odd -> kb2], K(p+2) -> ka,
    //                PV reads V(p) [even -> va],     V(p+1) -> vb
    iterBody(p, kb2, ka, va, vb);
    // odd iter p+1:  QK^T reads K(p+2) [even -> ka], K(p+3) -> kb2,
    //                PV reads V(p+1) [odd -> vb],    V(p+2) -> va
    iterBody(p + 1, ka, kb2, vb, va);
  }

  // ---- merge the two key-parity partials (waves wq and wq+4 share q-rows)
  float* dump = (float*)smem;  // 4 waves x 64 lanes x 36 f32 = 36864B
  __syncthreads();             // all waves done with final tile reads
  if (group == 1) {
    float* D = dump + wq * 2304 + lane * 36;
#pragma unroll
    for (int qt = 0; qt < 2; ++qt)
#pragma unroll
      for (int dt = 0; dt < 4; ++dt)
        *(f32x4*)(D + (qt * 4 + dt) * 4) = o[qt][dt];
    D[32] = mrun[0]; D[33] = lrun[0]; D[34] = mrun[1]; D[35] = lrun[1];
  }
  __syncthreads();
  _Float16* Ots = (_Float16*)(smem + 40960);  // [128][80] f16 = 20480B
  if (group == 0) {
    const float* D = dump + wq * 2304 + lane * 36;
#pragma unroll
    for (int qt = 0; qt < 2; ++qt) {
      const float m2 = D[32 + qt * 2], l2 = D[33 + qt * 2];
      const float mM = fmaxf(mrun[qt], m2);
      const float f1 = EXP2F(mrun[qt] - mM);
      const float f2 = EXP2F(m2 - mM);
      const float inv = 1.0f / (lrun[qt] * f1 + l2 * f2);
#pragma unroll
      for (int dt = 0; dt < 4; ++dt) {
        f32x4 o2 = *(const f32x4*)(D + (qt * 4 + dt) * 4);
#pragma unroll
        for (int r = 0; r < 4; ++r) {
          const float val = (o[qt][dt][r] * f1 + o2[r] * f2) * inv;
          Ots[(wq * 32 + qt * 16 + lq) * 80 + dt * 16 + quad * 4 + r] =
              (_Float16)val;
        }
      }
    }
  }
  __syncthreads();
  {
    const int row = t >> 2, seg = t & 3;
    const _Float16* src = &Ots[row * 80 + seg * 16];
    half8 o0 = ((const half8*)src)[0], o1 = ((const half8*)src)[1];
    _Float16* dst = ho + (rowbase + i0 + row) * DIM + head * 64 + seg * 16;
    ((half8*)dst)[0] = o0; ((half8*)dst)[1] = o1;
  }
}

// ---------------------------------------------------------------------------
// out = ho(fp16) @ w_out — 64x128 tile, swapped MFMA operands -> float4
// coalesced C stores; XCD-swizzled grid.
// ---------------------------------------------------------------------------
__global__ __launch_bounds__(256, 4) void gemm_out(
    const _Float16* __restrict__ A, const _Float16* __restrict__ BT,
    float* __restrict__ C) {
  __shared__ __align__(16) char smem[24576];  // 2 bufs: A 4KB | B 8KB
  const int t = threadIdx.x;
  const int lane = t & 63, wave = t >> 6, quad = lane >> 4, lq = lane & 15;
  // XCD swizzle: 512 blocks, 64 consecutive per XCD (8 bm x 8 bn).
  const int wid0 = blockIdx.x + 8 * blockIdx.y;
  const int wid = (wid0 & 7) * 64 + (wid0 >> 3);
  const int bn = (wid % 8) * 128, bm = (wid / 8) * 64;
  const int wm = (wave >> 1) * 32, wn = (wave & 1) * 64;

  const int bco = (lane & 7) ^ (lane >> 3);
  const int brow = 2 * (lane >> 3) + (bco >> 2);
  const int bcc = bco & 3;
  const _Float16* ag = A + (size_t)(bm + wave * 16 + brow) * DIM + bcc * 8;
  const _Float16* bg = BT + (size_t)(bn + wave * 32 + brow) * DIM + bcc * 8;
  const int swzB = ((((lq & 1) << 2) | quad) ^ ((lq >> 1) & 7)) * 8;

  auto issue = [&](char* buf, int k0) {
    ld_lds16(buf + wave * 1024,               ag + k0);
    ld_lds16(buf + 4096 + wave * 2048,        bg + k0);
    ld_lds16(buf + 4096 + wave * 2048 + 1024, bg + k0 + 16 * DIM);
  };

  f32x4 acc[2][4];
#pragma unroll
  for (int i = 0; i < 2; ++i)
#pragma unroll
    for (int j = 0; j < 4; ++j) acc[i][j] = (f32x4){0.f, 0.f, 0.f, 0.f};

  char* bufA = smem;
  char* bufB = smem + 12288;
  issue(bufA, 0);
  for (int k0 = 0; k0 < DIM; k0 += 32) {
    char* cur = ((k0 >> 5) & 1) ? bufB : bufA;
    char* nxt = ((k0 >> 5) & 1) ? bufA : bufB;
    __syncthreads();
    if (k0 + 32 < DIM) issue(nxt, k0 + 32);
    const _Float16* Ahs = (const _Float16*)cur;
    const _Float16* Bhs = (const _Float16*)(cur + 4096);
    half8 ah[2];
#pragma unroll
    for (int i = 0; i < 2; ++i) {
      const int row = wm + i * 16 + lq;
      ah[i] = *(const half8*)&Ahs[(row >> 1) * 64 + swzB];
    }
#pragma unroll
    for (int j = 0; j < 4; ++j) {
      const int row = wn + j * 16 + lq;
      half8 bf = *(const half8*)&Bhs[(row >> 1) * 64 + swzB];
#pragma unroll
      for (int i = 0; i < 2; ++i)
        acc[i][j] = MFMA_F16K32(bf, ah[i], acc[i][j]);  // swapped: row=lq
    }
  }
#pragma unroll
  for (int i = 0; i < 2; ++i) {
    const int row = bm + wm + i * 16 + lq;
#pragma unroll
    for (int j = 0; j < 4; ++j) {
      const int col = bn + wn + j * 16 + quad * 4;
      *(f32x4*)&C[(size_t)row * 1024 + col] = acc[i][j];
    }
  }
}

// ---------------------------------------------------------------------------
extern "C" void kernel_launch(void* const* d_in, const int* in_sizes, int n_in,
                              void* d_out, int out_size, void* d_ws,
                              size_t ws_size, hipStream_t stream) {
  const float* x     = (const float*)d_in[0];
  const float* w_q   = (const float*)d_in[1];
  const float* w_vk  = (const float*)d_in[2];
  const float* w_out = (const float*)d_in[3];
  float* out = (float*)d_out;

  char* w = (char*)d_ws;  // 48 MB used
  _Float16* wT  = (_Float16*)(w);                  // [3072][1024] 6MB
  _Float16* woT = (_Float16*)(w + (6ull << 20));   // [1024][1024] 2MB
  _Float16* qbb = (_Float16*)(w + (8ull << 20));   // [4096][1024] 8MB
  _Float16* kbb = (_Float16*)(w + (16ull << 20));  // [4096][1024] 8MB
  _Float16* vTb = (_Float16*)(w + (24ull << 20));  // [b][h][64][2048] 8MB
  _Float16* hob = (_Float16*)(w + (32ull << 20));  // [4096][1024] 8MB
  _Float16* xfb = (_Float16*)(w + (40ull << 20));  // [4096][1024] 8MB

  dim3 blk(256);
  prep<<<dim3(3072), blk, 0, stream>>>(w_q, w_vk, w_out, x, wT, woT, xfb);
  proj6<<<dim3(24, 32), blk, 0, stream>>>(xfb, wT, qbb, kbb, vTb);
  attn11<<<dim3(16, 32), dim3(512), 0, stream>>>(qbb, kbb, vTb, hob);
  gemm_out<<<dim3(8, 64), blk, 0, stream>>>(hob, woT, out);
}

// Round 11
// 178.942 us; speedup vs baseline: 1.9558x; 1.3328x over previous
//
#include <hip/hip_runtime.h>

typedef _Float16 half4 __attribute__((ext_vector_type(4)));
typedef _Float16 half8 __attribute__((ext_vector_type(8)));
typedef _Float16 h2pk __attribute__((ext_vector_type(2)));
typedef float f32x4 __attribute__((ext_vector_type(4)));

#define MFMA_F16K32(a, b, c) __builtin_amdgcn_mfma_f32_16x16x32_f16(a, b, c, 0, 0, 0)
#define EXP2F(x) __builtin_amdgcn_exp2f(x)
#define CVT_PK(a, b) __builtin_bit_cast(h2pk, __builtin_amdgcn_cvt_pkrtz(a, b))

constexpr int NSEQ = 2048, DIM = 1024;
constexpr float QSCALE = 11.5415603271f;  // 8 * log2(e): logits in log2 units

__device__ __forceinline__ void ld_lds16(void* lds, const void* g) {
  __builtin_amdgcn_global_load_lds(
      (const __attribute__((address_space(1))) void*)g,
      (__attribute__((address_space(3))) void*)lds, 16, 0, 0);
}

// ---------------------------------------------------------------------------
// prep: blocks 0..1023 transpose weights 64x64 -> fp16 WT[3072][1024] / WoT;
// blocks 1024..3071: x -> fp16.
// ---------------------------------------------------------------------------
__global__ __launch_bounds__(256) void prep(
    const float* __restrict__ w_q, const float* __restrict__ w_vk,
    const float* __restrict__ w_out, const float* __restrict__ x,
    _Float16* __restrict__ WT, _Float16* __restrict__ WoT,
    _Float16* __restrict__ xf) {
  const int bid = blockIdx.x;
  const int t = threadIdx.x;
  if (bid >= 1024) {  // ---- x -> fp16 ----
    const size_t i = ((size_t)(bid - 1024) * 256 + t) * 8;
    float4 a = *(const float4*)(x + i), b2 = *(const float4*)(x + i + 4);
    float v[8] = {a.x, a.y, a.z, a.w, b2.x, b2.y, b2.z, b2.w};
    half8 h;
#pragma unroll
    for (int j = 0; j < 8; ++j) h[j] = (_Float16)v[j];
    *(half8*)(xf + i) = h;
    return;
  }
  __shared__ float T[64][65];
  const int bx = bid & 63, k0 = (bid >> 6) * 64;
  const float* src;
  int srcN, n0, dstrow, mode;
  float scale;
  if (bx < 16) {
    src = w_q; srcN = 1024; n0 = bx * 64; dstrow = n0; scale = QSCALE; mode = 0;
  } else if (bx < 48) {
    src = w_vk; srcN = 2048; n0 = (bx - 16) * 64; dstrow = 1024 + n0;
    scale = 1.0f; mode = 0;
  } else {
    src = w_out; srcN = 1024; n0 = (bx - 48) * 64; dstrow = n0;
    scale = 1.0f; mode = 1;
  }
  {
    const int r = t >> 2, c4 = (t & 3) * 16;
    const float* s = src + (size_t)(k0 + r) * srcN + n0 + c4;
    float4 v0 = ((const float4*)s)[0], v1 = ((const float4*)s)[1],
           v2 = ((const float4*)s)[2], v3 = ((const float4*)s)[3];
    *(float4*)&T[r][c4 + 0] = v0;  *(float4*)&T[r][c4 + 4] = v1;
    *(float4*)&T[r][c4 + 8] = v2;  *(float4*)&T[r][c4 + 12] = v3;
  }
  __syncthreads();
  const int rn = t >> 2, kc = (t & 3) * 16;
  half8 hv[2];
#pragma unroll
  for (int hh = 0; hh < 2; ++hh)
#pragma unroll
    for (int j = 0; j < 8; ++j)
      hv[hh][j] = (_Float16)(T[kc + hh * 8 + j][rn] * scale);
  _Float16* d = ((mode == 0) ? WT + (size_t)(dstrow + rn) * 1024
                             : WoT + (size_t)(n0 + rn) * 1024) + k0 + kc;
  *(half8*)d = hv[0]; *(half8*)(d + 8) = hv[1];
}

// ---------------------------------------------------------------------------
// Fused q/k/v projection. 128x128 tile, BK=32, double-buffered, 4 blocks/CU,
// XCD-swizzled grid. q/k: swapped MFMA operands -> half4 coalesced stores.
// v: original orientation + LDS transpose -> coalesced vT stores.
// ---------------------------------------------------------------------------
__global__ __launch_bounds__(256, 4) void proj6(
    const _Float16* __restrict__ xf, const _Float16* __restrict__ WT,
    _Float16* __restrict__ qb, _Float16* __restrict__ kb,
    _Float16* __restrict__ VT) {
  __shared__ __align__(16) char smem[32768];  // 2 bufs x (X 8KB | B 8KB)
  const int t = threadIdx.x;
  const int lane = t & 63, wave = t >> 6, quad = lane >> 4, lq = lane & 15;
  // XCD swizzle: 768 blocks, 96 consecutive per XCD (4 bm x 24 bn).
  const int wid0 = blockIdx.x + 24 * blockIdx.y;
  const int wid = (wid0 & 7) * 96 + (wid0 >> 3);
  const int bn = (wid % 24) * 128, bm = (wid / 24) * 128;
  const int kind = bn >> 10;
  const int wm = (wave >> 1) * 64, wn = (wave & 1) * 64;

  // staging: 64B rows (32 fp16); one 1KB issue = 16 rows, 4 lanes/row.
  const int srow = lane >> 2;                // 0..15
  const int schk = (lane & 3) ^ (srow & 3);  // 16B chunk
  const _Float16* xg = xf + (size_t)(bm + wave * 32 + srow) * DIM + schk * 8;
  const _Float16* bg = WT + (size_t)(bn + wave * 32 + srow) * DIM + schk * 8;
  const int wb = wave * 2048;  // 32 rows x 64B

  auto issue = [&](char* buf, int k0) {
    ld_lds16(buf + wb,                xg + k0);
    ld_lds16(buf + wb + 1024,         xg + k0 + 16 * DIM);
    ld_lds16(buf + 8192 + wb,         bg + k0);
    ld_lds16(buf + 8192 + wb + 1024,  bg + k0 + 16 * DIM);
  };

  const int swz = (quad ^ (lq & 3)) * 8;  // chunk c of row r at c^(r&3)

  f32x4 acc[4][4];
#pragma unroll
  for (int i = 0; i < 4; ++i)
#pragma unroll
    for (int j = 0; j < 4; ++j) acc[i][j] = (f32x4){0.f, 0.f, 0.f, 0.f};

  char* bufA = smem;
  char* bufB = smem + 16384;
  issue(bufA, 0);
  if (kind == 2) {  // ---- v: original operand order ----
    for (int k0 = 0; k0 < DIM; k0 += 32) {
      char* cur = ((k0 >> 5) & 1) ? bufB : bufA;
      char* nxt = ((k0 >> 5) & 1) ? bufA : bufB;
      __syncthreads();
      if (k0 + 32 < DIM) issue(nxt, k0 + 32);
      const _Float16* Xs = (const _Float16*)cur;
      const _Float16* Bs = (const _Float16*)(cur + 8192);
      half8 ah[4];
#pragma unroll
      for (int i = 0; i < 4; ++i)
        ah[i] = *(const half8*)&Xs[(wm + i * 16 + lq) * 32 + swz];
#pragma unroll
      for (int j = 0; j < 4; ++j) {
        half8 bf = *(const half8*)&Bs[(wn + j * 16 + lq) * 32 + swz];
#pragma unroll
        for (int i = 0; i < 4; ++i)
          acc[i][j] = MFMA_F16K32(ah[i], bf, acc[i][j]);
      }
    }
  } else {  // ---- q/k: swapped operands (token=lq, col=quad*4+r) ----
    for (int k0 = 0; k0 < DIM; k0 += 32) {
      char* cur = ((k0 >> 5) & 1) ? bufB : bufA;
      char* nxt = ((k0 >> 5) & 1) ? bufA : bufB;
      __syncthreads();
      if (k0 + 32 < DIM) issue(nxt, k0 + 32);
      const _Float16* Xs = (const _Float16*)cur;
      const _Float16* Bs = (const _Float16*)(cur + 8192);
      half8 ah[4];
#pragma unroll
      for (int i = 0; i < 4; ++i)
        ah[i] = *(const half8*)&Xs[(wm + i * 16 + lq) * 32 + swz];
#pragma unroll
      for (int j = 0; j < 4; ++j) {
        half8 bf = *(const half8*)&Bs[(wn + j * 16 + lq) * 32 + swz];
#pragma unroll
        for (int i = 0; i < 4; ++i)
          acc[i][j] = MFMA_F16K32(bf, ah[i], acc[i][j]);
      }
    }
  }

  if (kind == 2) {
    // v -> vT[b][h][d][n] via LDS transpose; two 64-token passes.
    _Float16* Ols = (_Float16*)smem;  // 128*68*2 = 17408B <= 32KB
    const int cb = bn - 2048;         // global col base (h*64+d space)
    __syncthreads();                  // all waves done reading K-loop bufs
#pragma unroll
    for (int pass = 0; pass < 2; ++pass) {
      if ((wave >> 1) == pass) {  // waves whose wm == pass*64
#pragma unroll
        for (int i = 0; i < 4; ++i)
#pragma unroll
          for (int j = 0; j < 4; ++j) {
            const int c = wn + j * 16 + lq;    // 0..127
            const int tl = i * 16 + quad * 4;  // token local 0..63
            half4 o;
#pragma unroll
            for (int r = 0; r < 4; ++r) o[r] = (_Float16)acc[i][j][r];
            *(half4*)&Ols[c * 68 + tl] = o;
          }
      }
      __syncthreads();
      {
        const int c = t >> 1, hf = t & 1;  // c 0..127, 32-token half
        const int gcol = cb + c;
        const int tok0 = bm + pass * 64 + hf * 32;
        const int b2 = tok0 >> 11, n2 = tok0 & 2047;
        const _Float16* src = &Ols[c * 68 + hf * 32];
        half8 v0 = ((const half8*)src)[0], v1 = ((const half8*)src)[1],
              v2 = ((const half8*)src)[2], v3 = ((const half8*)src)[3];
        _Float16* dst =
            VT + ((size_t)(b2 * 16 + (gcol >> 6)) * 64 + (gcol & 63)) * 2048 + n2;
        ((half8*)dst)[0] = v0; ((half8*)dst)[1] = v1;
        ((half8*)dst)[2] = v2; ((half8*)dst)[3] = v3;
      }
      __syncthreads();  // before next pass overwrites Ols
    }
  } else {
    // q/k coalesced: half4 over r = 4 consecutive cols; 16 rows x 32B/inst.
    _Float16* D = (kind == 0) ? qb : kb;
    const int cb = bn & 1023;
#pragma unroll
    for (int i = 0; i < 4; ++i) {
      const int row = bm + wm + i * 16 + lq;
#pragma unroll
      for (int j = 0; j < 4; ++j) {
        const int col = cb + wn + j * 16 + quad * 4;
        half4 o;
#pragma unroll
        for (int r = 0; r < 4; ++r) o[r] = (_Float16)acc[i][j][r];
        *(half4*)&D[(size_t)row * 1024 + col] = o;
      }
    }
  }
}

// ---------------------------------------------------------------------------
// Flash attention attn9 (round-7/8 body — best measured, 57.2-59.1us):
// key-parity wave split (8 waves x 32 q-rows, TJ=64, 2 blocks/CU), K32 PV
// via per-tile key permutation kappa (zero cross-lane P handling), XCD
// swizzle (FETCH 70->12MB). Two T15 pipeline attempts (r9/r10) both hit
// scratch spill — qt=2 state leaves no VGPR headroom for cross-iteration
// score lifetimes at 4 waves/SIMD. Do not re-attempt without cutting state.
// ---------------------------------------------------------------------------
__global__ __launch_bounds__(512, 4) void attn9(
    const _Float16* __restrict__ qb, const _Float16* __restrict__ kb,
    const _Float16* __restrict__ vT, _Float16* __restrict__ ho) {
  __shared__ __align__(16) char smem[65536];
  const int t = threadIdx.x;
  const int lane = t & 63, wave = t >> 6, quad = lane >> 4, lq = lane & 15;
  const int group = wave >> 2, wq = wave & 3;
  const int wid = blockIdx.x + 16 * blockIdx.y;  // 0..511
  const int xcd = wid & 7, slot = wid >> 3;      // slot 0..63
  const int i0 = (slot & 15) * 128;
  const int bh = xcd + 8 * (slot >> 4);
  const int b = bh >> 4, head = bh & 15;
  const size_t rowbase = (size_t)b * NSEQ;

  half8 qf[2][2];
#pragma unroll
  for (int qt = 0; qt < 2; ++qt) {
    const _Float16* qp =
        qb + (rowbase + i0 + wq * 32 + qt * 16 + lq) * DIM + head * 64 + quad * 8;
    qf[qt][0] = *(const half8*)qp;
    qf[qt][1] = *(const half8*)(qp + 32);
  }

  f32x4 o[2][4];
#pragma unroll
  for (int qt = 0; qt < 2; ++qt)
#pragma unroll
    for (int dt = 0; dt < 4; ++dt) o[qt][dt] = (f32x4){0.f, 0.f, 0.f, 0.f};
  float mrun[2] = {-3.0e38f, -3.0e38f};
  float lrun[2] = {0.f, 0.f};

  const int srow = lane >> 3, schk = (lane & 7) ^ srow;
  const int krow = (wq >> 1) * 32 + (wq & 1) * 4 + ((srow & 4) << 1) + (srow & 3);
  const _Float16* kgp =
      kb + (rowbase + krow) * DIM + head * 64 + schk * 8;
  const int vrow = lane >> 3;
  const int vchk = (lane & 7) ^ vrow;
  const _Float16* vgp =
      vT + ((size_t)bh * 64 + wq * 16 + vrow) * 2048 + vchk * 8;

  auto issue = [&](int bsel, int j) {
    char* kd = smem + (group * 2 + bsel) * 8192 + wq * 2048;
    char* vd = kd + 32768;
    ld_lds16(kd,        kgp + (size_t)(j)      * DIM);
    ld_lds16(kd + 1024, kgp + (size_t)(j + 16) * DIM);
    ld_lds16(vd,        vgp + j);
    ld_lds16(vd + 1024, vgp + 8 * 2048 + j);
  };

  const int swzK0 = (quad ^ (lq & 7)) * 8;
  const int swzK1 = ((quad + 4) ^ (lq & 7)) * 8;

  issue(0, group * 64);

  for (int p = 0; p < 16; ++p) {
    const int cur = p & 1;
    __syncthreads();
    if (p < 15) issue(cur ^ 1, (2 * p + group) * 64 + 128);
    const _Float16* Khs = (const _Float16*)(smem + (group * 2 + cur) * 8192);
    const _Float16* Vts = (const _Float16*)(smem + 32768 + (group * 2 + cur) * 8192);

    f32x4 s[2][4];
    __builtin_amdgcn_s_setprio(1);
#pragma unroll
    for (int nt = 0; nt < 4; ++nt) {
      const int roff = (nt * 16 + lq) * 64;
      half8 k0f = *(const half8*)&Khs[roff + swzK0];
      half8 k1f = *(const half8*)&Khs[roff + swzK1];
#pragma unroll
      for (int qt = 0; qt < 2; ++qt) {
        f32x4 sv = (f32x4){0.f, 0.f, 0.f, 0.f};
        sv = MFMA_F16K32(k0f, qf[qt][0], sv);
        sv = MFMA_F16K32(k1f, qf[qt][1], sv);
        s[qt][nt] = sv;
      }
    }
    __builtin_amdgcn_s_setprio(0);

    half8 pa8[2][2];
#pragma unroll
    for (int qt = 0; qt < 2; ++qt) {
      float m0 = fmaxf(fmaxf(s[qt][0][0], s[qt][0][1]),
                       fmaxf(s[qt][0][2], s[qt][0][3]));
      float m1 = fmaxf(fmaxf(s[qt][1][0], s[qt][1][1]),
                       fmaxf(s[qt][1][2], s[qt][1][3]));
      float m2 = fmaxf(fmaxf(s[qt][2][0], s[qt][2][1]),
                       fmaxf(s[qt][2][2], s[qt][2][3]));
      float m3 = fmaxf(fmaxf(s[qt][3][0], s[qt][3][1]),
                       fmaxf(s[qt][3][2], s[qt][3][3]));
      float mx = fmaxf(fmaxf(m0, m1), fmaxf(m2, m3));
      mx = fmaxf(mx, __shfl_xor(mx, 16));
      mx = fmaxf(mx, __shfl_xor(mx, 32));
      const float mn = fmaxf(mrun[qt], mx);
      const float alpha = EXP2F(mrun[qt] - mn);
      mrun[qt] = mn;
      float rs = 0.f;
#pragma unroll
      for (int nt = 0; nt < 4; ++nt) {
        float p0 = EXP2F(s[qt][nt][0] - mn), p1 = EXP2F(s[qt][nt][1] - mn);
        float p2 = EXP2F(s[qt][nt][2] - mn), p3 = EXP2F(s[qt][nt][3] - mn);
        rs += (p0 + p1) + (p2 + p3);
        h2pk lo = CVT_PK(p0, p1);
        h2pk hi = CVT_PK(p2, p3);
        const int bb = nt >> 1, e = (nt & 1) * 4;
        pa8[qt][bb][e + 0] = lo[0]; pa8[qt][bb][e + 1] = lo[1];
        pa8[qt][bb][e + 2] = hi[0]; pa8[qt][bb][e + 3] = hi[1];
      }
      rs += __shfl_xor(rs, 16);
      rs += __shfl_xor(rs, 32);
      lrun[qt] = lrun[qt] * alpha + rs;
#pragma unroll
      for (int dt = 0; dt < 4; ++dt) o[qt][dt] *= alpha;
    }

    __builtin_amdgcn_s_setprio(1);
#pragma unroll
    for (int dt = 0; dt < 4; ++dt) {
      const int vr2 = (dt * 16 + lq) * 64;
#pragma unroll
      for (int bb = 0; bb < 2; ++bb) {
        const int voff = vr2 + (((bb * 4 + quad) ^ (lq & 7)) * 8);
        half8 va = *(const half8*)&Vts[voff];
        o[0][dt] = MFMA_F16K32(va, pa8[0][bb], o[0][dt]);
        o[1][dt] = MFMA_F16K32(va, pa8[1][bb], o[1][dt]);
      }
    }
    __builtin_amdgcn_s_setprio(0);
  }

  float* dump = (float*)smem;
  __syncthreads();
  if (group == 1) {
    float* D = dump + wq * 2304 + lane * 36;
#pragma unroll
    for (int qt = 0; qt < 2; ++qt)
#pragma unroll
      for (int dt = 0; dt < 4; ++dt)
        *(f32x4*)(D + (qt * 4 + dt) * 4) = o[qt][dt];
    D[32] = mrun[0]; D[33] = lrun[0]; D[34] = mrun[1]; D[35] = lrun[1];
  }
  __syncthreads();
  _Float16* Ots = (_Float16*)(smem + 40960);
  if (group == 0) {
    const float* D = dump + wq * 2304 + lane * 36;
#pragma unroll
    for (int qt = 0; qt < 2; ++qt) {
      const float m2 = D[32 + qt * 2], l2 = D[33 + qt * 2];
      const float mM = fmaxf(mrun[qt], m2);
      const float f1 = EXP2F(mrun[qt] - mM);
      const float f2 = EXP2F(m2 - mM);
      const float inv = 1.0f / (lrun[qt] * f1 + l2 * f2);
#pragma unroll
      for (int dt = 0; dt < 4; ++dt) {
        f32x4 o2 = *(const f32x4*)(D + (qt * 4 + dt) * 4);
#pragma unroll
        for (int r = 0; r < 4; ++r) {
          const float val = (o[qt][dt][r] * f1 + o2[r] * f2) * inv;
          Ots[(wq * 32 + qt * 16 + lq) * 80 + dt * 16 + quad * 4 + r] =
              (_Float16)val;
        }
      }
    }
  }
  __syncthreads();
  {
    const int row = t >> 2, seg = t & 3;
    const _Float16* src = &Ots[row * 80 + seg * 16];
    half8 o0 = ((const half8*)src)[0], o1 = ((const half8*)src)[1];
    _Float16* dst = ho + (rowbase + i0 + row) * DIM + head * 64 + seg * 16;
    ((half8*)dst)[0] = o0; ((half8*)dst)[1] = o1;
  }
}

// ---------------------------------------------------------------------------
// out = ho(fp16) @ w_out — 64x128 tile, swapped MFMA operands -> float4
// coalesced C stores; XCD-swizzled grid.
// ---------------------------------------------------------------------------
__global__ __launch_bounds__(256, 4) void gemm_out(
    const _Float16* __restrict__ A, const _Float16* __restrict__ BT,
    float* __restrict__ C) {
  __shared__ __align__(16) char smem[24576];  // 2 bufs: A 4KB | B 8KB
  const int t = threadIdx.x;
  const int lane = t & 63, wave = t >> 6, quad = lane >> 4, lq = lane & 15;
  // XCD swizzle: 512 blocks, 64 consecutive per XCD (8 bm x 8 bn).
  const int wid0 = blockIdx.x + 8 * blockIdx.y;
  const int wid = (wid0 & 7) * 64 + (wid0 >> 3);
  const int bn = (wid % 8) * 128, bm = (wid / 8) * 64;
  const int wm = (wave >> 1) * 32, wn = (wave & 1) * 64;

  const int bco = (lane & 7) ^ (lane >> 3);
  const int brow = 2 * (lane >> 3) + (bco >> 2);
  const int bcc = bco & 3;
  const _Float16* ag = A + (size_t)(bm + wave * 16 + brow) * DIM + bcc * 8;
  const _Float16* bg = BT + (size_t)(bn + wave * 32 + brow) * DIM + bcc * 8;
  const int swzB = ((((lq & 1) << 2) | quad) ^ ((lq >> 1) & 7)) * 8;

  auto issue = [&](char* buf, int k0) {
    ld_lds16(buf + wave * 1024,               ag + k0);
    ld_lds16(buf + 4096 + wave * 2048,        bg + k0);
    ld_lds16(buf + 4096 + wave * 2048 + 1024, bg + k0 + 16 * DIM);
  };

  f32x4 acc[2][4];
#pragma unroll
  for (int i = 0; i < 2; ++i)
#pragma unroll
    for (int j = 0; j < 4; ++j) acc[i][j] = (f32x4){0.f, 0.f, 0.f, 0.f};

  char* bufA = smem;
  char* bufB = smem + 12288;
  issue(bufA, 0);
  for (int k0 = 0; k0 < DIM; k0 += 32) {
    char* cur = ((k0 >> 5) & 1) ? bufB : bufA;
    char* nxt = ((k0 >> 5) & 1) ? bufA : bufB;
    __syncthreads();
    if (k0 + 32 < DIM) issue(nxt, k0 + 32);
    const _Float16* Ahs = (const _Float16*)cur;
    const _Float16* Bhs = (const _Float16*)(cur + 4096);
    half8 ah[2];
#pragma unroll
    for (int i = 0; i < 2; ++i) {
      const int row = wm + i * 16 + lq;
      ah[i] = *(const half8*)&Ahs[(row >> 1) * 64 + swzB];
    }
#pragma unroll
    for (int j = 0; j < 4; ++j) {
      const int row = wn + j * 16 + lq;
      half8 bf = *(const half8*)&Bhs[(row >> 1) * 64 + swzB];
#pragma unroll
      for (int i = 0; i < 2; ++i)
        acc[i][j] = MFMA_F16K32(bf, ah[i], acc[i][j]);  // swapped: row=lq
    }
  }
#pragma unroll
  for (int i = 0; i < 2; ++i) {
    const int row = bm + wm + i * 16 + lq;
#pragma unroll
    for (int j = 0; j < 4; ++j) {
      const int col = bn + wn + j * 16 + quad * 4;
      *(f32x4*)&C[(size_t)row * 1024 + col] = acc[i][j];
    }
  }
}

// ---------------------------------------------------------------------------
extern "C" void kernel_launch(void* const* d_in, const int* in_sizes, int n_in,
                              void* d_out, int out_size, void* d_ws,
                              size_t ws_size, hipStream_t stream) {
  const float* x     = (const float*)d_in[0];
  const float* w_q   = (const float*)d_in[1];
  const float* w_vk  = (const float*)d_in[2];
  const float* w_out = (const float*)d_in[3];
  float* out = (float*)d_out;

  char* w = (char*)d_ws;  // 48 MB used
  _Float16* wT  = (_Float16*)(w);                  // [3072][1024] 6MB
  _Float16* woT = (_Float16*)(w + (6ull << 20));   // [1024][1024] 2MB
  _Float16* qbb = (_Float16*)(w + (8ull << 20));   // [4096][1024] 8MB
  _Float16* kbb = (_Float16*)(w + (16ull << 20));  // [4096][1024] 8MB
  _Float16* vTb = (_Float16*)(w + (24ull << 20));  // [b][h][64][2048] 8MB
  _Float16* hob = (_Float16*)(w + (32ull << 20));  // [4096][1024] 8MB
  _Float16* xfb = (_Float16*)(w + (40ull << 20));  // [4096][1024] 8MB

  dim3 blk(256);
  prep<<<dim3(3072), blk, 0, stream>>>(w_q, w_vk, w_out, x, wT, woT, xfb);
  proj6<<<dim3(24, 32), blk, 0, stream>>>(xfb, wT, qbb, kbb, vTb);
  attn9<<<dim3(16, 32), dim3(512), 0, stream>>>(qbb, kbb, vTb, hob);
  gemm_out<<<dim3(8, 64), blk, 0, stream>>>(hob, woT, out);
}

// Round 12
// 177.925 us; speedup vs baseline: 1.9670x; 1.0057x over previous
//
#include <hip/hip_runtime.h>

typedef _Float16 half4 __attribute__((ext_vector_type(4)));
typedef _Float16 half8 __attribute__((ext_vector_type(8)));
typedef _Float16 h2pk __attribute__((ext_vector_type(2)));
typedef float f32x2 __attribute__((ext_vector_type(2)));
typedef float f32x4 __attribute__((ext_vector_type(4)));

#define MFMA_F16K32(a, b, c) __builtin_amdgcn_mfma_f32_16x16x32_f16(a, b, c, 0, 0, 0)
#define EXP2F(x) __builtin_amdgcn_exp2f(x)
#define CVT_PK(a, b) __builtin_bit_cast(h2pk, __builtin_amdgcn_cvt_pkrtz(a, b))
#define LO2(v) __builtin_shufflevector(v, v, 0, 1)
#define HI2(v) __builtin_shufflevector(v, v, 2, 3)

// Packed-f32 VALU (CDNA, MI200+): 2 f32 ops per issue slot. The compiler
// never auto-forms these; operands here are already adjacent (MFMA f32x4
// halves), so no extra movs on the inputs.
__device__ __forceinline__ f32x2 pk_add(f32x2 a, f32x2 b) {
  f32x2 d;
  asm("v_pk_add_f32 %0, %1, %2" : "=v"(d) : "v"(a), "v"(b));
  return d;
}
__device__ __forceinline__ f32x2 pk_mul(f32x2 a, f32x2 b) {
  f32x2 d;
  asm("v_pk_mul_f32 %0, %1, %2" : "=v"(d) : "v"(a), "v"(b));
  return d;
}

constexpr int NSEQ = 2048, DIM = 1024;
constexpr float QSCALE = 11.5415603271f;  // 8 * log2(e): logits in log2 units

__device__ __forceinline__ void ld_lds16(void* lds, const void* g) {
  __builtin_amdgcn_global_load_lds(
      (const __attribute__((address_space(1))) void*)g,
      (__attribute__((address_space(3))) void*)lds, 16, 0, 0);
}

// ---------------------------------------------------------------------------
// prep: blocks 0..1023 transpose weights 64x64 -> fp16 WT[3072][1024] / WoT;
// blocks 1024..3071: x -> fp16.
// ---------------------------------------------------------------------------
__global__ __launch_bounds__(256) void prep(
    const float* __restrict__ w_q, const float* __restrict__ w_vk,
    const float* __restrict__ w_out, const float* __restrict__ x,
    _Float16* __restrict__ WT, _Float16* __restrict__ WoT,
    _Float16* __restrict__ xf) {
  const int bid = blockIdx.x;
  const int t = threadIdx.x;
  if (bid >= 1024) {  // ---- x -> fp16 ----
    const size_t i = ((size_t)(bid - 1024) * 256 + t) * 8;
    float4 a = *(const float4*)(x + i), b2 = *(const float4*)(x + i + 4);
    float v[8] = {a.x, a.y, a.z, a.w, b2.x, b2.y, b2.z, b2.w};
    half8 h;
#pragma unroll
    for (int j = 0; j < 8; ++j) h[j] = (_Float16)v[j];
    *(half8*)(xf + i) = h;
    return;
  }
  __shared__ float T[64][65];
  const int bx = bid & 63, k0 = (bid >> 6) * 64;
  const float* src;
  int srcN, n0, dstrow, mode;
  float scale;
  if (bx < 16) {
    src = w_q; srcN = 1024; n0 = bx * 64; dstrow = n0; scale = QSCALE; mode = 0;
  } else if (bx < 48) {
    src = w_vk; srcN = 2048; n0 = (bx - 16) * 64; dstrow = 1024 + n0;
    scale = 1.0f; mode = 0;
  } else {
    src = w_out; srcN = 1024; n0 = (bx - 48) * 64; dstrow = n0;
    scale = 1.0f; mode = 1;
  }
  {
    const int r = t >> 2, c4 = (t & 3) * 16;
    const float* s = src + (size_t)(k0 + r) * srcN + n0 + c4;
    float4 v0 = ((const float4*)s)[0], v1 = ((const float4*)s)[1],
           v2 = ((const float4*)s)[2], v3 = ((const float4*)s)[3];
    *(float4*)&T[r][c4 + 0] = v0;  *(float4*)&T[r][c4 + 4] = v1;
    *(float4*)&T[r][c4 + 8] = v2;  *(float4*)&T[r][c4 + 12] = v3;
  }
  __syncthreads();
  const int rn = t >> 2, kc = (t & 3) * 16;
  half8 hv[2];
#pragma unroll
  for (int hh = 0; hh < 2; ++hh)
#pragma unroll
    for (int j = 0; j < 8; ++j)
      hv[hh][j] = (_Float16)(T[kc + hh * 8 + j][rn] * scale);
  _Float16* d = ((mode == 0) ? WT + (size_t)(dstrow + rn) * 1024
                             : WoT + (size_t)(n0 + rn) * 1024) + k0 + kc;
  *(half8*)d = hv[0]; *(half8*)(d + 8) = hv[1];
}

// ---------------------------------------------------------------------------
// Fused q/k/v projection. 128x128 tile, BK=32, double-buffered, 4 blocks/CU,
// XCD-swizzled grid. q/k: swapped MFMA operands -> half4 coalesced stores.
// v: original orientation + LDS transpose -> coalesced vT stores.
// ---------------------------------------------------------------------------
__global__ __launch_bounds__(256, 4) void proj6(
    const _Float16* __restrict__ xf, const _Float16* __restrict__ WT,
    _Float16* __restrict__ qb, _Float16* __restrict__ kb,
    _Float16* __restrict__ VT) {
  __shared__ __align__(16) char smem[32768];  // 2 bufs x (X 8KB | B 8KB)
  const int t = threadIdx.x;
  const int lane = t & 63, wave = t >> 6, quad = lane >> 4, lq = lane & 15;
  // XCD swizzle: 768 blocks, 96 consecutive per XCD (4 bm x 24 bn).
  const int wid0 = blockIdx.x + 24 * blockIdx.y;
  const int wid = (wid0 & 7) * 96 + (wid0 >> 3);
  const int bn = (wid % 24) * 128, bm = (wid / 24) * 128;
  const int kind = bn >> 10;
  const int wm = (wave >> 1) * 64, wn = (wave & 1) * 64;

  // staging: 64B rows (32 fp16); one 1KB issue = 16 rows, 4 lanes/row.
  const int srow = lane >> 2;                // 0..15
  const int schk = (lane & 3) ^ (srow & 3);  // 16B chunk
  const _Float16* xg = xf + (size_t)(bm + wave * 32 + srow) * DIM + schk * 8;
  const _Float16* bg = WT + (size_t)(bn + wave * 32 + srow) * DIM + schk * 8;
  const int wb = wave * 2048;  // 32 rows x 64B

  auto issue = [&](char* buf, int k0) {
    ld_lds16(buf + wb,                xg + k0);
    ld_lds16(buf + wb + 1024,         xg + k0 + 16 * DIM);
    ld_lds16(buf + 8192 + wb,         bg + k0);
    ld_lds16(buf + 8192 + wb + 1024,  bg + k0 + 16 * DIM);
  };

  const int swz = (quad ^ (lq & 3)) * 8;  // chunk c of row r at c^(r&3)

  f32x4 acc[4][4];
#pragma unroll
  for (int i = 0; i < 4; ++i)
#pragma unroll
    for (int j = 0; j < 4; ++j) acc[i][j] = (f32x4){0.f, 0.f, 0.f, 0.f};

  char* bufA = smem;
  char* bufB = smem + 16384;
  issue(bufA, 0);
  if (kind == 2) {  // ---- v: original operand order ----
    for (int k0 = 0; k0 < DIM; k0 += 32) {
      char* cur = ((k0 >> 5) & 1) ? bufB : bufA;
      char* nxt = ((k0 >> 5) & 1) ? bufA : bufB;
      __syncthreads();
      if (k0 + 32 < DIM) issue(nxt, k0 + 32);
      const _Float16* Xs = (const _Float16*)cur;
      const _Float16* Bs = (const _Float16*)(cur + 8192);
      half8 ah[4];
#pragma unroll
      for (int i = 0; i < 4; ++i)
        ah[i] = *(const half8*)&Xs[(wm + i * 16 + lq) * 32 + swz];
#pragma unroll
      for (int j = 0; j < 4; ++j) {
        half8 bf = *(const half8*)&Bs[(wn + j * 16 + lq) * 32 + swz];
#pragma unroll
        for (int i = 0; i < 4; ++i)
          acc[i][j] = MFMA_F16K32(ah[i], bf, acc[i][j]);
      }
    }
  } else {  // ---- q/k: swapped operands (token=lq, col=quad*4+r) ----
    for (int k0 = 0; k0 < DIM; k0 += 32) {
      char* cur = ((k0 >> 5) & 1) ? bufB : bufA;
      char* nxt = ((k0 >> 5) & 1) ? bufA : bufB;
      __syncthreads();
      if (k0 + 32 < DIM) issue(nxt, k0 + 32);
      const _Float16* Xs = (const _Float16*)cur;
      const _Float16* Bs = (const _Float16*)(cur + 8192);
      half8 ah[4];
#pragma unroll
      for (int i = 0; i < 4; ++i)
        ah[i] = *(const half8*)&Xs[(wm + i * 16 + lq) * 32 + swz];
#pragma unroll
      for (int j = 0; j < 4; ++j) {
        half8 bf = *(const half8*)&Bs[(wn + j * 16 + lq) * 32 + swz];
#pragma unroll
        for (int i = 0; i < 4; ++i)
          acc[i][j] = MFMA_F16K32(bf, ah[i], acc[i][j]);
      }
    }
  }

  if (kind == 2) {
    // v -> vT[b][h][d][n] via LDS transpose; two 64-token passes.
    _Float16* Ols = (_Float16*)smem;  // 128*68*2 = 17408B <= 32KB
    const int cb = bn - 2048;         // global col base (h*64+d space)
    __syncthreads();                  // all waves done reading K-loop bufs
#pragma unroll
    for (int pass = 0; pass < 2; ++pass) {
      if ((wave >> 1) == pass) {  // waves whose wm == pass*64
#pragma unroll
        for (int i = 0; i < 4; ++i)
#pragma unroll
          for (int j = 0; j < 4; ++j) {
            const int c = wn + j * 16 + lq;    // 0..127
            const int tl = i * 16 + quad * 4;  // token local 0..63
            half4 o;
#pragma unroll
            for (int r = 0; r < 4; ++r) o[r] = (_Float16)acc[i][j][r];
            *(half4*)&Ols[c * 68 + tl] = o;
          }
      }
      __syncthreads();
      {
        const int c = t >> 1, hf = t & 1;  // c 0..127, 32-token half
        const int gcol = cb + c;
        const int tok0 = bm + pass * 64 + hf * 32;
        const int b2 = tok0 >> 11, n2 = tok0 & 2047;
        const _Float16* src = &Ols[c * 68 + hf * 32];
        half8 v0 = ((const half8*)src)[0], v1 = ((const half8*)src)[1],
              v2 = ((const half8*)src)[2], v3 = ((const half8*)src)[3];
        _Float16* dst =
            VT + ((size_t)(b2 * 16 + (gcol >> 6)) * 64 + (gcol & 63)) * 2048 + n2;
        ((half8*)dst)[0] = v0; ((half8*)dst)[1] = v1;
        ((half8*)dst)[2] = v2; ((half8*)dst)[3] = v3;
      }
      __syncthreads();  // before next pass overwrites Ols
    }
  } else {
    // q/k coalesced: half4 over r = 4 consecutive cols; 16 rows x 32B/inst.
    _Float16* D = (kind == 0) ? qb : kb;
    const int cb = bn & 1023;
#pragma unroll
    for (int i = 0; i < 4; ++i) {
      const int row = bm + wm + i * 16 + lq;
#pragma unroll
      for (int j = 0; j < 4; ++j) {
        const int col = cb + wn + j * 16 + quad * 4;
        half4 o;
#pragma unroll
        for (int r = 0; r < 4; ++r) o[r] = (_Float16)acc[i][j][r];
        *(half4*)&D[(size_t)row * 1024 + col] = o;
      }
    }
  }
}

// ---------------------------------------------------------------------------
// Flash attention attn12 = attn9 (round-7/8 body, 56us) + packed-f32 softmax:
// s-mn via v_pk_add_f32 (16 vs 32 slots), o-rescale via v_pk_mul_f32 (16 vs
// 32), max3-fusable reduce tree (~8 vs 15). Operands already paired (MFMA
// f32x4 halves). exp2/cvt_pk/rs-sum stay scalar (fresh scalars; pairing
// would add movs). Everything else identical to the verified attn9.
// ---------------------------------------------------------------------------
__global__ __launch_bounds__(512, 4) void attn12(
    const _Float16* __restrict__ qb, const _Float16* __restrict__ kb,
    const _Float16* __restrict__ vT, _Float16* __restrict__ ho) {
  __shared__ __align__(16) char smem[65536];
  const int t = threadIdx.x;
  const int lane = t & 63, wave = t >> 6, quad = lane >> 4, lq = lane & 15;
  const int group = wave >> 2, wq = wave & 3;
  const int wid = blockIdx.x + 16 * blockIdx.y;  // 0..511
  const int xcd = wid & 7, slot = wid >> 3;      // slot 0..63
  const int i0 = (slot & 15) * 128;
  const int bh = xcd + 8 * (slot >> 4);
  const int b = bh >> 4, head = bh & 15;
  const size_t rowbase = (size_t)b * NSEQ;

  half8 qf[2][2];
#pragma unroll
  for (int qt = 0; qt < 2; ++qt) {
    const _Float16* qp =
        qb + (rowbase + i0 + wq * 32 + qt * 16 + lq) * DIM + head * 64 + quad * 8;
    qf[qt][0] = *(const half8*)qp;
    qf[qt][1] = *(const half8*)(qp + 32);
  }

  f32x4 o[2][4];
#pragma unroll
  for (int qt = 0; qt < 2; ++qt)
#pragma unroll
    for (int dt = 0; dt < 4; ++dt) o[qt][dt] = (f32x4){0.f, 0.f, 0.f, 0.f};
  float mrun[2] = {-3.0e38f, -3.0e38f};
  float lrun[2] = {0.f, 0.f};

  const int srow = lane >> 3, schk = (lane & 7) ^ srow;
  const int krow = (wq >> 1) * 32 + (wq & 1) * 4 + ((srow & 4) << 1) + (srow & 3);
  const _Float16* kgp =
      kb + (rowbase + krow) * DIM + head * 64 + schk * 8;
  const int vrow = lane >> 3;
  const int vchk = (lane & 7) ^ vrow;
  const _Float16* vgp =
      vT + ((size_t)bh * 64 + wq * 16 + vrow) * 2048 + vchk * 8;

  auto issue = [&](int bsel, int j) {
    char* kd = smem + (group * 2 + bsel) * 8192 + wq * 2048;
    char* vd = kd + 32768;
    ld_lds16(kd,        kgp + (size_t)(j)      * DIM);
    ld_lds16(kd + 1024, kgp + (size_t)(j + 16) * DIM);
    ld_lds16(vd,        vgp + j);
    ld_lds16(vd + 1024, vgp + 8 * 2048 + j);
  };

  const int swzK0 = (quad ^ (lq & 7)) * 8;
  const int swzK1 = ((quad + 4) ^ (lq & 7)) * 8;

  issue(0, group * 64);

  for (int p = 0; p < 16; ++p) {
    const int cur = p & 1;
    __syncthreads();
    if (p < 15) issue(cur ^ 1, (2 * p + group) * 64 + 128);
    const _Float16* Khs = (const _Float16*)(smem + (group * 2 + cur) * 8192);
    const _Float16* Vts = (const _Float16*)(smem + 32768 + (group * 2 + cur) * 8192);

    f32x4 s[2][4];
    __builtin_amdgcn_s_setprio(1);
#pragma unroll
    for (int nt = 0; nt < 4; ++nt) {
      const int roff = (nt * 16 + lq) * 64;
      half8 k0f = *(const half8*)&Khs[roff + swzK0];
      half8 k1f = *(const half8*)&Khs[roff + swzK1];
#pragma unroll
      for (int qt = 0; qt < 2; ++qt) {
        f32x4 sv = (f32x4){0.f, 0.f, 0.f, 0.f};
        sv = MFMA_F16K32(k0f, qf[qt][0], sv);
        sv = MFMA_F16K32(k1f, qf[qt][1], sv);
        s[qt][nt] = sv;
      }
    }
    __builtin_amdgcn_s_setprio(0);

    half8 pa8[2][2];
#pragma unroll
    for (int qt = 0; qt < 2; ++qt) {
      // max3-fusable tree over the 16 lane-resident scores
      float a0 = fmaxf(fmaxf(s[qt][0][0], s[qt][0][1]), s[qt][0][2]);
      float a1 = fmaxf(fmaxf(s[qt][0][3], s[qt][1][0]), s[qt][1][1]);
      float a2 = fmaxf(fmaxf(s[qt][1][2], s[qt][1][3]), s[qt][2][0]);
      float a3 = fmaxf(fmaxf(s[qt][2][1], s[qt][2][2]), s[qt][2][3]);
      float a4 = fmaxf(fmaxf(s[qt][3][0], s[qt][3][1]), s[qt][3][2]);
      float mx = fmaxf(fmaxf(fmaxf(a0, a1), a2),
                       fmaxf(fmaxf(a3, a4), s[qt][3][3]));
      mx = fmaxf(mx, __shfl_xor(mx, 16));
      mx = fmaxf(mx, __shfl_xor(mx, 32));
      const float mn = fmaxf(mrun[qt], mx);
      const float alpha = EXP2F(mrun[qt] - mn);
      mrun[qt] = mn;
      const float nmn = -mn;
      const f32x2 nm = {nmn, nmn};
      float rs = 0.f;
#pragma unroll
      for (int nt = 0; nt < 4; ++nt) {
        f32x2 dlo = pk_add(LO2(s[qt][nt]), nm);   // s - mn, 2 per slot
        f32x2 dhi = pk_add(HI2(s[qt][nt]), nm);
        float p0 = EXP2F(dlo[0]), p1 = EXP2F(dlo[1]);
        float p2 = EXP2F(dhi[0]), p3 = EXP2F(dhi[1]);
        rs += (p0 + p1) + (p2 + p3);
        h2pk lo = CVT_PK(p0, p1);
        h2pk hi = CVT_PK(p2, p3);
        const int bb = nt >> 1, e = (nt & 1) * 4;
        pa8[qt][bb][e + 0] = lo[0]; pa8[qt][bb][e + 1] = lo[1];
        pa8[qt][bb][e + 2] = hi[0]; pa8[qt][bb][e + 3] = hi[1];
      }
      rs += __shfl_xor(rs, 16);
      rs += __shfl_xor(rs, 32);
      lrun[qt] = lrun[qt] * alpha + rs;
      const f32x2 af = {alpha, alpha};
#pragma unroll
      for (int dt = 0; dt < 4; ++dt) {
        f32x2 olo = pk_mul(LO2(o[qt][dt]), af);   // o *= alpha, 2 per slot
        f32x2 ohi = pk_mul(HI2(o[qt][dt]), af);
        f32x4 on;
        on[0] = olo[0]; on[1] = olo[1]; on[2] = ohi[0]; on[3] = ohi[1];
        o[qt][dt] = on;
      }
    }

    __builtin_amdgcn_s_setprio(1);
#pragma unroll
    for (int dt = 0; dt < 4; ++dt) {
      const int vr2 = (dt * 16 + lq) * 64;
#pragma unroll
      for (int bb = 0; bb < 2; ++bb) {
        const int voff = vr2 + (((bb * 4 + quad) ^ (lq & 7)) * 8);
        half8 va = *(const half8*)&Vts[voff];
        o[0][dt] = MFMA_F16K32(va, pa8[0][bb], o[0][dt]);
        o[1][dt] = MFMA_F16K32(va, pa8[1][bb], o[1][dt]);
      }
    }
    __builtin_amdgcn_s_setprio(0);
  }

  float* dump = (float*)smem;
  __syncthreads();
  if (group == 1) {
    float* D = dump + wq * 2304 + lane * 36;
#pragma unroll
    for (int qt = 0; qt < 2; ++qt)
#pragma unroll
      for (int dt = 0; dt < 4; ++dt)
        *(f32x4*)(D + (qt * 4 + dt) * 4) = o[qt][dt];
    D[32] = mrun[0]; D[33] = lrun[0]; D[34] = mrun[1]; D[35] = lrun[1];
  }
  __syncthreads();
  _Float16* Ots = (_Float16*)(smem + 40960);
  if (group == 0) {
    const float* D = dump + wq * 2304 + lane * 36;
#pragma unroll
    for (int qt = 0; qt < 2; ++qt) {
      const float m2 = D[32 + qt * 2], l2 = D[33 + qt * 2];
      const float mM = fmaxf(mrun[qt], m2);
      const float f1 = EXP2F(mrun[qt] - mM);
      const float f2 = EXP2F(m2 - mM);
      const float inv = 1.0f / (lrun[qt] * f1 + l2 * f2);
#pragma unroll
      for (int dt = 0; dt < 4; ++dt) {
        f32x4 o2 = *(const f32x4*)(D + (qt * 4 + dt) * 4);
#pragma unroll
        for (int r = 0; r < 4; ++r) {
          const float val = (o[qt][dt][r] * f1 + o2[r] * f2) * inv;
          Ots[(wq * 32 + qt * 16 + lq) * 80 + dt * 16 + quad * 4 + r] =
              (_Float16)val;
        }
      }
    }
  }
  __syncthreads();
  {
    const int row = t >> 2, seg = t & 3;
    const _Float16* src = &Ots[row * 80 + seg * 16];
    half8 o0 = ((const half8*)src)[0], o1 = ((const half8*)src)[1];
    _Float16* dst = ho + (rowbase + i0 + row) * DIM + head * 64 + seg * 16;
    ((half8*)dst)[0] = o0; ((half8*)dst)[1] = o1;
  }
}

// ---------------------------------------------------------------------------
// out = ho(fp16) @ w_out — 64x128 tile, swapped MFMA operands -> float4
// coalesced C stores; XCD-swizzled grid.
// ---------------------------------------------------------------------------
__global__ __launch_bounds__(256, 4) void gemm_out(
    const _Float16* __restrict__ A, const _Float16* __restrict__ BT,
    float* __restrict__ C) {
  __shared__ __align__(16) char smem[24576];  // 2 bufs: A 4KB | B 8KB
  const int t = threadIdx.x;
  const int lane = t & 63, wave = t >> 6, quad = lane >> 4, lq = lane & 15;
  // XCD swizzle: 512 blocks, 64 consecutive per XCD (8 bm x 8 bn).
  const int wid0 = blockIdx.x + 8 * blockIdx.y;
  const int wid = (wid0 & 7) * 64 + (wid0 >> 3);
  const int bn = (wid % 8) * 128, bm = (wid / 8) * 64;
  const int wm = (wave >> 1) * 32, wn = (wave & 1) * 64;

  const int bco = (lane & 7) ^ (lane >> 3);
  const int brow = 2 * (lane >> 3) + (bco >> 2);
  const int bcc = bco & 3;
  const _Float16* ag = A + (size_t)(bm + wave * 16 + brow) * DIM + bcc * 8;
  const _Float16* bg = BT + (size_t)(bn + wave * 32 + brow) * DIM + bcc * 8;
  const int swzB = ((((lq & 1) << 2) | quad) ^ ((lq >> 1) & 7)) * 8;

  auto issue = [&](char* buf, int k0) {
    ld_lds16(buf + wave * 1024,               ag + k0);
    ld_lds16(buf + 4096 + wave * 2048,        bg + k0);
    ld_lds16(buf + 4096 + wave * 2048 + 1024, bg + k0 + 16 * DIM);
  };

  f32x4 acc[2][4];
#pragma unroll
  for (int i = 0; i < 2; ++i)
#pragma unroll
    for (int j = 0; j < 4; ++j) acc[i][j] = (f32x4){0.f, 0.f, 0.f, 0.f};

  char* bufA = smem;
  char* bufB = smem + 12288;
  issue(bufA, 0);
  for (int k0 = 0; k0 < DIM; k0 += 32) {
    char* cur = ((k0 >> 5) & 1) ? bufB : bufA;
    char* nxt = ((k0 >> 5) & 1) ? bufA : bufB;
    __syncthreads();
    if (k0 + 32 < DIM) issue(nxt, k0 + 32);
    const _Float16* Ahs = (const _Float16*)cur;
    const _Float16* Bhs = (const _Float16*)(cur + 4096);
    half8 ah[2];
#pragma unroll
    for (int i = 0; i < 2; ++i) {
      const int row = wm + i * 16 + lq;
      ah[i] = *(const half8*)&Ahs[(row >> 1) * 64 + swzB];
    }
#pragma unroll
    for (int j = 0; j < 4; ++j) {
      const int row = wn + j * 16 + lq;
      half8 bf = *(const half8*)&Bhs[(row >> 1) * 64 + swzB];
#pragma unroll
      for (int i = 0; i < 2; ++i)
        acc[i][j] = MFMA_F16K32(bf, ah[i], acc[i][j]);  // swapped: row=lq
    }
  }
#pragma unroll
  for (int i = 0; i < 2; ++i) {
    const int row = bm + wm + i * 16 + lq;
#pragma unroll
    for (int j = 0; j < 4; ++j) {
      const int col = bn + wn + j * 16 + quad * 4;
      *(f32x4*)&C[(size_t)row * 1024 + col] = acc[i][j];
    }
  }
}

// ---------------------------------------------------------------------------
extern "C" void kernel_launch(void* const* d_in, const int* in_sizes, int n_in,
                              void* d_out, int out_size, void* d_ws,
                              size_t ws_size, hipStream_t stream) {
  const float* x     = (const float*)d_in[0];
  const float* w_q   = (const float*)d_in[1];
  const float* w_vk  = (const float*)d_in[2];
  const float* w_out = (const float*)d_in[3];
  float* out = (float*)d_out;

  char* w = (char*)d_ws;  // 48 MB used
  _Float16* wT  = (_Float16*)(w);                  // [3072][1024] 6MB
  _Float16* woT = (_Float16*)(w + (6ull << 20));   // [1024][1024] 2MB
  _Float16* qbb = (_Float16*)(w + (8ull << 20));   // [4096][1024] 8MB
  _Float16* kbb = (_Float16*)(w + (16ull << 20));  // [4096][1024] 8MB
  _Float16* vTb = (_Float16*)(w + (24ull << 20));  // [b][h][64][2048] 8MB
  _Float16* hob = (_Float16*)(w + (32ull << 20));  // [4096][1024] 8MB
  _Float16* xfb = (_Float16*)(w + (40ull << 20));  // [4096][1024] 8MB

  dim3 blk(256);
  prep<<<dim3(3072), blk, 0, stream>>>(w_q, w_vk, w_out, x, wT, woT, xfb);
  proj6<<<dim3(24, 32), blk, 0, stream>>>(xfb, wT, qbb, kbb, vTb);
  attn12<<<dim3(16, 32), dim3(512), 0, stream>>>(qbb, kbb, vTb, hob);
  gemm_out<<<dim3(8, 64), blk, 0, stream>>>(hob, woT, out);
}